// Round 4
// baseline (2542.652 us; speedup 1.0000x reference)
//
#include <hip/hip_runtime.h>

#define NN 50000
#define EE 800000
#define DD 128
#define KT 32
#define NKT 4   // 128 / KT

// ---------------- prep_ab : A = nd@Mw[0:128] ; B = nd@Mw[128:256] + Mb -------------
__global__ __launch_bounds__(256) void prep_ab(
    const float* __restrict__ nd, const float* __restrict__ Mw,
    const float* __restrict__ Mb, float* __restrict__ A, float* __restrict__ B) {
  __shared__ float xs[32][DD];
  __shared__ float wsA[KT][DD];
  __shared__ float wsB[KT][DD];
  const int t = threadIdx.x;
  const int c = t & 127;
  const int rh = (t >> 7) * 16;
  const int row0 = blockIdx.x * 32;
  const float4* U4 = (const float4*)Mw;

  #pragma unroll
  for (int j = 0; j < 4; j++) {
    int q = t + j * 256;
    int r = q >> 5, cc4 = q & 31;
    int n = row0 + r;
    float4 v = {0.f, 0.f, 0.f, 0.f};
    if (n < NN) v = ((const float4*)nd)[n * 32 + cc4];
    ((float4*)xs)[q] = v;
  }

  float accA[16], accB[16];
  #pragma unroll
  for (int r = 0; r < 16; r++) { accA[r] = 0.f; accB[r] = 0.f; }

  float4 pfA[4], pfB[4];
  #pragma unroll
  for (int j = 0; j < 4; j++) {
    pfA[j] = U4[t + j * 256];
    pfB[j] = U4[128 * 32 + t + j * 256];
  }
  for (int kt = 0; kt < NKT; kt++) {
    __syncthreads();
    #pragma unroll
    for (int j = 0; j < 4; j++) {
      ((float4*)wsA)[t + j * 256] = pfA[j];
      ((float4*)wsB)[t + j * 256] = pfB[j];
    }
    __syncthreads();
    if (kt + 1 < NKT) {
      int ko = (kt + 1) * KT;
      #pragma unroll
      for (int j = 0; j < 4; j++) {
        pfA[j] = U4[ko * 32 + t + j * 256];
        pfB[j] = U4[(128 + ko) * 32 + t + j * 256];
      }
    }
    #pragma unroll
    for (int kg = 0; kg < KT / 4; kg++) {
      float wa[4], wb[4];
      #pragma unroll
      for (int j = 0; j < 4; j++) { wa[j] = wsA[kg * 4 + j][c]; wb[j] = wsB[kg * 4 + j][c]; }
      #pragma unroll
      for (int r = 0; r < 16; r++) {
        float4 x = *(const float4*)&xs[rh + r][kt * KT + kg * 4];
        accA[r] += x.x * wa[0] + x.y * wa[1] + x.z * wa[2] + x.w * wa[3];
        accB[r] += x.x * wb[0] + x.y * wb[1] + x.z * wb[2] + x.w * wb[3];
      }
    }
  }
  float mb = Mb[c];
  #pragma unroll
  for (int r = 0; r < 16; r++) {
    int n = row0 + rh + r;
    if (n < NN) { A[n * DD + c] = accA[r]; B[n * DD + c] = accB[r] + mb; }
  }
}

__global__ __launch_bounds__(256) void init_small(
    unsigned int* __restrict__ cnt, float* __restrict__ bns, float* __restrict__ bnq) {
  int i = blockIdx.x * 256 + threadIdx.x;
  if (i < NN) cnt[i] = 0u;
  if (i < DD) { bns[i] = 0.f; bnq[i] = 0.f; }
}

__global__ __launch_bounds__(256) void deg_count(
    const int* __restrict__ dst, unsigned int* __restrict__ cnt) {
  int e = blockIdx.x * 256 + threadIdx.x;
  if (e < EE) atomicAdd(&cnt[dst[e]], 1u);
}

// single-workgroup exclusive scan of cnt[NN] -> off, cursor
__global__ __launch_bounds__(1024) void scan_k(
    const unsigned int* __restrict__ cnt, unsigned int* __restrict__ off,
    unsigned int* __restrict__ cursor) {
  __shared__ unsigned int part[1024];
  const int t = threadIdx.x;
  const int CH = (NN + 1023) / 1024;
  int beg = t * CH, end = beg + CH;
  if (end > NN) end = NN;
  unsigned int s = 0;
  for (int i = beg; i < end; i++) s += cnt[i];
  part[t] = s;
  __syncthreads();
  for (int d = 1; d < 1024; d <<= 1) {
    unsigned int v = (t >= d) ? part[t - d] : 0u;
    __syncthreads();
    part[t] += v;
    __syncthreads();
  }
  unsigned int run = part[t] - s;
  for (int i = beg; i < end; i++) {
    off[i] = run; cursor[i] = run; run += cnt[i];
  }
  if (t == 0) off[NN] = EE;
}

__global__ __launch_bounds__(256) void fill_k(
    const int* __restrict__ src, const int* __restrict__ dst,
    unsigned int* __restrict__ cursor, unsigned int* __restrict__ eidx) {
  int e = blockIdx.x * 256 + threadIdx.x;
  if (e < EE) {
    unsigned int p = atomicAdd(&cursor[dst[e]], 1u);
    eidx[p] = (unsigned int)src[e];
  }
}

// gather-aggregate: one wave per node; sum/max of A[src] rows (+ self loop),
// then S = sum/deg + B ; Xm = max + B ; amp = log(deg+1)/2.5
__global__ __launch_bounds__(256) void aggregate(
    const float* __restrict__ A, const float* __restrict__ Bv,
    const unsigned int* __restrict__ off, const unsigned int* __restrict__ eidx,
    float* __restrict__ S, float* __restrict__ Xm, float* __restrict__ amp) {
  int wave = threadIdx.x >> 6, lane = threadIdx.x & 63;
  int n = blockIdx.x * 4 + wave;
  if (n >= NN) return;
  unsigned int b0 = off[n], b1 = off[n + 1];
  float2 sum = ((const float2*)(A + (size_t)n * DD))[lane];
  float2 mx = sum;
  for (unsigned int j0 = b0; j0 < b1; j0 += 64) {
    int m = (int)min(64u, b1 - j0);
    int myi = (lane < m) ? (int)eidx[j0 + lane] : 0;
    for (int j = 0; j < m; j++) {
      int sN = __shfl(myi, j);
      float2 a = ((const float2*)(A + (size_t)sN * DD))[lane];
      sum.x += a.x; sum.y += a.y;
      mx.x = fmaxf(mx.x, a.x); mx.y = fmaxf(mx.y, a.y);
    }
  }
  float degf = (float)(b1 - b0) + 1.f;
  float inv = 1.f / degf;
  float2 b = ((const float2*)(Bv + (size_t)n * DD))[lane];
  float2 sm = {sum.x * inv + b.x, sum.y * inv + b.y};
  float2 xm = {mx.x + b.x, mx.y + b.y};
  ((float2*)(S + (size_t)n * DD))[lane] = sm;
  ((float2*)(Xm + (size_t)n * DD))[lane] = xm;
  if (lane == 0) amp[n] = logf(degf + 1.f) * 0.4f;
}

// H = nd@W0 + S@(W1+W3) + amp*S@(W4+W6) + Xm@W2 + amp*Xm@W5 + Ub ; fused BN stats
__global__ __launch_bounds__(256) void u_matmul(
    const float* __restrict__ nd, const float* __restrict__ S,
    const float* __restrict__ Xm, const float* __restrict__ amp,
    const float* __restrict__ Uw, const float* __restrict__ Ub,
    float* __restrict__ H, float* __restrict__ bns, float* __restrict__ bnq) {
  __shared__ float xs[32][DD];
  __shared__ float wsI[KT][DD];
  __shared__ float wsM[KT][DD];
  const int t = threadIdx.x;
  const int c = t & 127;
  const int rh = (t >> 7) * 16;
  const int row0 = blockIdx.x * 32;
  const float4* U4 = (const float4*)Uw;

  float acc[16], ampv[16];
  #pragma unroll
  for (int r = 0; r < 16; r++) {
    acc[r] = 0.f;
    int n = row0 + rh + r;
    ampv[r] = (n < NN) ? amp[n] : 0.f;
  }

  #pragma unroll
  for (int p = 0; p < 3; p++) {
    const float* srcp = (p == 0) ? nd : (p == 1) ? S : Xm;
    const int ia = (p == 0) ? 0 : (p == 1) ? 128 : 256;
    const int ib = (p == 1) ? 384 : -1;
    const int aa = (p == 1) ? 512 : 640;
    const int ab = (p == 1) ? 768 : -1;
    const bool dual = (p > 0);

    __syncthreads();  // previous panel's compute done before overwriting xs
    #pragma unroll
    for (int j = 0; j < 4; j++) {
      int q = t + j * 256;
      int r = q >> 5, cc4 = q & 31;
      int n = row0 + r;
      float4 v = {0.f, 0.f, 0.f, 0.f};
      if (n < NN) v = ((const float4*)srcp)[n * 32 + cc4];
      ((float4*)xs)[q] = v;
    }

    float acc2[16];
    #pragma unroll
    for (int r = 0; r < 16; r++) acc2[r] = 0.f;

    float4 pfI[4], pfM[4];
    #pragma unroll
    for (int j = 0; j < 4; j++) {
      float4 v = U4[ia * 32 + t + j * 256];
      if (ib >= 0) {
        float4 u = U4[ib * 32 + t + j * 256];
        v.x += u.x; v.y += u.y; v.z += u.z; v.w += u.w;
      }
      pfI[j] = v;
      if (dual) {
        float4 w = U4[aa * 32 + t + j * 256];
        if (ab >= 0) {
          float4 u = U4[ab * 32 + t + j * 256];
          w.x += u.x; w.y += u.y; w.z += u.z; w.w += u.w;
        }
        pfM[j] = w;
      }
    }
    for (int kt = 0; kt < NKT; kt++) {
      __syncthreads();
      #pragma unroll
      for (int j = 0; j < 4; j++) {
        ((float4*)wsI)[t + j * 256] = pfI[j];
        if (dual) ((float4*)wsM)[t + j * 256] = pfM[j];
      }
      __syncthreads();
      if (kt + 1 < NKT) {
        int ko = (kt + 1) * KT;
        #pragma unroll
        for (int j = 0; j < 4; j++) {
          float4 v = U4[(ia + ko) * 32 + t + j * 256];
          if (ib >= 0) {
            float4 u = U4[(ib + ko) * 32 + t + j * 256];
            v.x += u.x; v.y += u.y; v.z += u.z; v.w += u.w;
          }
          pfI[j] = v;
          if (dual) {
            float4 w = U4[(aa + ko) * 32 + t + j * 256];
            if (ab >= 0) {
              float4 u = U4[(ab + ko) * 32 + t + j * 256];
              w.x += u.x; w.y += u.y; w.z += u.z; w.w += u.w;
            }
            pfM[j] = w;
          }
        }
      }
      #pragma unroll
      for (int kg = 0; kg < KT / 4; kg++) {
        float wi[4], wm[4];
        #pragma unroll
        for (int j = 0; j < 4; j++) {
          wi[j] = wsI[kg * 4 + j][c];
          wm[j] = dual ? wsM[kg * 4 + j][c] : 0.f;
        }
        #pragma unroll
        for (int r = 0; r < 16; r++) {
          float4 x = *(const float4*)&xs[rh + r][kt * KT + kg * 4];
          acc[r] += x.x * wi[0] + x.y * wi[1] + x.z * wi[2] + x.w * wi[3];
          if (dual) acc2[r] += x.x * wm[0] + x.y * wm[1] + x.z * wm[2] + x.w * wm[3];
        }
      }
    }
    if (dual) {
      #pragma unroll
      for (int r = 0; r < 16; r++) acc[r] += ampv[r] * acc2[r];
    }
  }
  float ub = Ub[c];
  float sS = 0.f, sQ = 0.f;
  #pragma unroll
  for (int r = 0; r < 16; r++) {
    int n = row0 + rh + r;
    if (n < NN) {
      float h = acc[r] + ub;
      H[n * DD + c] = h;
      sS += h; sQ += h * h;
    }
  }
  atomicAdd(bns + c, sS);
  atomicAdd(bnq + c, sQ);
}

// out = leaky_relu( BN(H) @ mw + mb )
__global__ __launch_bounds__(256) void final_k(
    const float* __restrict__ H, const float* __restrict__ bns, const float* __restrict__ bnq,
    const float* __restrict__ gamma, const float* __restrict__ beta,
    const float* __restrict__ mw, const float* __restrict__ mb,
    float* __restrict__ out) {
  __shared__ float xs[32][DD];
  __shared__ float wsW[KT][DD];
  const int t = threadIdx.x;
  const int c = t & 127;
  const int rh = (t >> 7) * 16;
  const int row0 = blockIdx.x * 32;
  const float4* W4 = (const float4*)mw;
  const int cc4 = t & 31;

  const float inv = 1.f / (float)NN;
  float4 sb = ((const float4*)bns)[cc4];
  float4 qb = ((const float4*)bnq)[cc4];
  float4 g4 = ((const float4*)gamma)[cc4];
  float4 b4 = ((const float4*)beta)[cc4];
  float4 a4, o4;
  {
    float mu, var;
    mu = sb.x * inv; var = qb.x * inv - mu * mu; a4.x = g4.x * rsqrtf(var + 1e-5f); o4.x = b4.x - mu * a4.x;
    mu = sb.y * inv; var = qb.y * inv - mu * mu; a4.y = g4.y * rsqrtf(var + 1e-5f); o4.y = b4.y - mu * a4.y;
    mu = sb.z * inv; var = qb.z * inv - mu * mu; a4.z = g4.z * rsqrtf(var + 1e-5f); o4.z = b4.z - mu * a4.z;
    mu = sb.w * inv; var = qb.w * inv - mu * mu; a4.w = g4.w * rsqrtf(var + 1e-5f); o4.w = b4.w - mu * a4.w;
  }
  #pragma unroll
  for (int j = 0; j < 4; j++) {
    int q = t + j * 256;
    int r = q >> 5;
    int n = row0 + r;
    float4 v = {0.f, 0.f, 0.f, 0.f};
    if (n < NN) {
      float4 h = ((const float4*)H)[n * 32 + cc4];
      v.x = a4.x * h.x + o4.x;
      v.y = a4.y * h.y + o4.y;
      v.z = a4.z * h.z + o4.z;
      v.w = a4.w * h.w + o4.w;
    }
    ((float4*)xs)[q] = v;
  }

  float acc[16];
  #pragma unroll
  for (int r = 0; r < 16; r++) acc[r] = 0.f;

  float4 pfW[4];
  #pragma unroll
  for (int j = 0; j < 4; j++) pfW[j] = W4[t + j * 256];
  for (int kt = 0; kt < NKT; kt++) {
    __syncthreads();
    #pragma unroll
    for (int j = 0; j < 4; j++) ((float4*)wsW)[t + j * 256] = pfW[j];
    __syncthreads();
    if (kt + 1 < NKT) {
      int ko = (kt + 1) * KT;
      #pragma unroll
      for (int j = 0; j < 4; j++) pfW[j] = W4[ko * 32 + t + j * 256];
    }
    #pragma unroll
    for (int kg = 0; kg < KT / 4; kg++) {
      float w[4];
      #pragma unroll
      for (int j = 0; j < 4; j++) w[j] = wsW[kg * 4 + j][c];
      #pragma unroll
      for (int r = 0; r < 16; r++) {
        float4 x = *(const float4*)&xs[rh + r][kt * KT + kg * 4];
        acc[r] += x.x * w[0] + x.y * w[1] + x.z * w[2] + x.w * w[3];
      }
    }
  }
  float mbv = mb[c];
  #pragma unroll
  for (int r = 0; r < 16; r++) {
    int n = row0 + rh + r;
    if (n < NN) {
      float o = acc[r] + mbv;
      o = o > 0.f ? o : 0.01f * o;
      out[n * DD + c] = o;
    }
  }
}

extern "C" void kernel_launch(void* const* d_in, const int* in_sizes, int n_in,
                              void* d_out, int out_size, void* d_ws, size_t ws_size,
                              hipStream_t stream) {
  const float* nd    = (const float*)d_in[0];
  const float* Mw    = (const float*)d_in[1];
  const float* Mb    = (const float*)d_in[2];
  const float* Uw    = (const float*)d_in[3];
  const float* Ub    = (const float*)d_in[4];
  const float* gamma = (const float*)d_in[5];
  const float* beta  = (const float*)d_in[6];
  const float* mixw  = (const float*)d_in[7];
  const float* mixb  = (const float*)d_in[8];
  const int* src = (const int*)d_in[9];
  const int* dst = (const int*)d_in[10];
  float* out = (float*)d_out;

  float* ws  = (float*)d_ws;
  float* A   = ws;
  float* Bv  = A + NN * DD;
  float* S   = Bv + NN * DD;
  float* Xm  = S + NN * DD;
  float* H   = Xm + NN * DD;
  float* amp = H + NN * DD;
  float* bns = amp + NN;
  float* bnq = bns + DD;
  unsigned int* cnt    = (unsigned int*)(bnq + DD);
  unsigned int* off    = cnt + NN;
  unsigned int* cursor = off + NN + 1;
  unsigned int* eidx   = cursor + NN;

  const int MB = (NN + 31) / 32;  // 1563 row-blocks
  prep_ab<<<MB, 256, 0, stream>>>(nd, Mw, Mb, A, Bv);
  init_small<<<(NN + 255) / 256, 256, 0, stream>>>(cnt, bns, bnq);
  deg_count<<<(EE + 255) / 256, 256, 0, stream>>>(dst, cnt);
  scan_k<<<1, 1024, 0, stream>>>(cnt, off, cursor);
  fill_k<<<(EE + 255) / 256, 256, 0, stream>>>(src, dst, cursor, eidx);
  aggregate<<<(NN + 3) / 4, 256, 0, stream>>>(A, Bv, off, eidx, S, Xm, amp);
  u_matmul<<<MB, 256, 0, stream>>>(nd, S, Xm, amp, Uw, Ub, H, bns, bnq);
  final_k<<<MB, 256, 0, stream>>>(H, bns, bnq, gamma, beta, mixw, mixb, out);
}

// Round 5
// 1986.472 us; speedup vs baseline: 1.2800x; 1.2800x over previous
//
#include <hip/hip_runtime.h>

#define NN 50000
#define EE 800000
#define DD 128
#define KT 32
#define NKT 4   // 128 / KT

// Uc = [W0 ; W1+W3 ; W4+W6 ; W2 ; W5]  (640 x 128), matching xs panel order
// nd, S, amp*S, Xm, amp*Xm
__global__ __launch_bounds__(256) void combine_w(
    const float* __restrict__ Uw, float* __restrict__ Uc) {
  int i = blockIdx.x * 256 + threadIdx.x;
  if (i >= 5 * DD * DD) return;
  int p = i / (DD * DD);
  int rc = i - p * (DD * DD);
  float v;
  switch (p) {
    case 0: v = Uw[rc]; break;
    case 1: v = Uw[128 * DD + rc] + Uw[384 * DD + rc]; break;
    case 2: v = Uw[512 * DD + rc] + Uw[768 * DD + rc]; break;
    case 3: v = Uw[256 * DD + rc]; break;
    default: v = Uw[640 * DD + rc]; break;
  }
  Uc[i] = v;
}

// ---- prep_ab : A = nd@Mw[0:128] ; B = nd@Mw[128:256] + Mb ----
// 256 thr, 32 rows x 128 cols per block; thread tile 4 rows x 4 cols.
__global__ __launch_bounds__(256) void prep_ab(
    const float* __restrict__ nd, const float* __restrict__ Mw,
    const float* __restrict__ Mb, float* __restrict__ A, float* __restrict__ B) {
  __shared__ float xs[32][DD];
  __shared__ float wsW[KT][DD];
  const int t = threadIdx.x;
  const int cg = t & 31;          // col-group (float4)
  const int c0 = cg * 4;
  const int r0 = (t >> 5) * 4;    // 8 row-groups of 4
  const int row0 = blockIdx.x * 32;
  const float4* W4 = (const float4*)Mw;

  #pragma unroll
  for (int j = 0; j < 4; j++) {
    int q = t + j * 256;
    int n = row0 + (q >> 5);
    float4 v = {0.f, 0.f, 0.f, 0.f};
    if (n < NN) v = ((const float4*)nd)[n * 32 + (q & 31)];
    ((float4*)xs)[q] = v;
  }

  float4 mb4 = *(const float4*)&Mb[c0];

  #pragma unroll
  for (int pass = 0; pass < 2; pass++) {
    float acc[4][4];
    #pragma unroll
    for (int ri = 0; ri < 4; ri++)
      #pragma unroll
      for (int cj = 0; cj < 4; cj++) acc[ri][cj] = 0.f;

    float4 wreg[4];
    #pragma unroll
    for (int j = 0; j < 4; j++) wreg[j] = W4[(pass * 128) * 32 + t + j * 256];

    for (int kt = 0; kt < NKT; kt++) {
      __syncthreads();
      #pragma unroll
      for (int j = 0; j < 4; j++) ((float4*)wsW)[t + j * 256] = wreg[j];
      __syncthreads();
      if (kt + 1 < NKT) {
        #pragma unroll
        for (int j = 0; j < 4; j++)
          wreg[j] = W4[(pass * 128 + (kt + 1) * KT) * 32 + t + j * 256];
      }
      #pragma unroll
      for (int kg = 0; kg < KT / 4; kg++) {
        float4 w[4];
        #pragma unroll
        for (int j = 0; j < 4; j++) w[j] = *(const float4*)&wsW[kg * 4 + j][c0];
        #pragma unroll
        for (int ri = 0; ri < 4; ri++) {
          float4 x = *(const float4*)&xs[r0 + ri][kt * KT + kg * 4];
          acc[ri][0] += x.x * w[0].x + x.y * w[1].x + x.z * w[2].x + x.w * w[3].x;
          acc[ri][1] += x.x * w[0].y + x.y * w[1].y + x.z * w[2].y + x.w * w[3].y;
          acc[ri][2] += x.x * w[0].z + x.y * w[1].z + x.z * w[2].z + x.w * w[3].z;
          acc[ri][3] += x.x * w[0].w + x.y * w[1].w + x.z * w[2].w + x.w * w[3].w;
        }
      }
    }
    float* dstp = (pass == 0) ? A : B;
    #pragma unroll
    for (int ri = 0; ri < 4; ri++) {
      int n = row0 + r0 + ri;
      if (n < NN) {
        float4 o;
        o.x = acc[ri][0]; o.y = acc[ri][1]; o.z = acc[ri][2]; o.w = acc[ri][3];
        if (pass == 1) { o.x += mb4.x; o.y += mb4.y; o.z += mb4.z; o.w += mb4.w; }
        ((float4*)dstp)[n * 32 + cg] = o;
      }
    }
  }
}

__global__ __launch_bounds__(256) void init_small(
    unsigned int* __restrict__ cnt, float* __restrict__ bns, float* __restrict__ bnq) {
  int i = blockIdx.x * 256 + threadIdx.x;
  if (i < NN) cnt[i] = 0u;
  if (i < DD) { bns[i] = 0.f; bnq[i] = 0.f; }
}

__global__ __launch_bounds__(256) void deg_count(
    const int* __restrict__ dst, unsigned int* __restrict__ cnt) {
  int e = blockIdx.x * 256 + threadIdx.x;
  if (e < EE) atomicAdd(&cnt[dst[e]], 1u);
}

__global__ __launch_bounds__(1024) void scan_k(
    const unsigned int* __restrict__ cnt, unsigned int* __restrict__ off,
    unsigned int* __restrict__ cursor) {
  __shared__ unsigned int part[1024];
  const int t = threadIdx.x;
  const int CH = (NN + 1023) / 1024;
  int beg = t * CH, end = beg + CH;
  if (end > NN) end = NN;
  unsigned int s = 0;
  for (int i = beg; i < end; i++) s += cnt[i];
  part[t] = s;
  __syncthreads();
  for (int d = 1; d < 1024; d <<= 1) {
    unsigned int v = (t >= d) ? part[t - d] : 0u;
    __syncthreads();
    part[t] += v;
    __syncthreads();
  }
  unsigned int run = part[t] - s;
  for (int i = beg; i < end; i++) {
    off[i] = run; cursor[i] = run; run += cnt[i];
  }
  if (t == 0) off[NN] = EE;
}

__global__ __launch_bounds__(256) void fill_k(
    const int* __restrict__ src, const int* __restrict__ dst,
    unsigned int* __restrict__ cursor, unsigned int* __restrict__ eidx) {
  int e = blockIdx.x * 256 + threadIdx.x;
  if (e < EE) {
    unsigned int p = atomicAdd(&cursor[dst[e]], 1u);
    eidx[p] = (unsigned int)src[e];
  }
}

// gather-aggregate: one wave per node
__global__ __launch_bounds__(256) void aggregate(
    const float* __restrict__ A, const float* __restrict__ Bv,
    const unsigned int* __restrict__ off, const unsigned int* __restrict__ eidx,
    float* __restrict__ S, float* __restrict__ Xm, float* __restrict__ amp) {
  int wave = threadIdx.x >> 6, lane = threadIdx.x & 63;
  int n = blockIdx.x * 4 + wave;
  if (n >= NN) return;
  unsigned int b0 = off[n], b1 = off[n + 1];
  float2 sum = ((const float2*)(A + (size_t)n * DD))[lane];
  float2 mx = sum;
  for (unsigned int j0 = b0; j0 < b1; j0 += 64) {
    int m = (int)min(64u, b1 - j0);
    int myi = (lane < m) ? (int)eidx[j0 + lane] : 0;
    for (int j = 0; j < m; j++) {
      int sN = __shfl(myi, j);
      float2 a = ((const float2*)(A + (size_t)sN * DD))[lane];
      sum.x += a.x; sum.y += a.y;
      mx.x = fmaxf(mx.x, a.x); mx.y = fmaxf(mx.y, a.y);
    }
  }
  float degf = (float)(b1 - b0) + 1.f;
  float inv = 1.f / degf;
  float2 b = ((const float2*)(Bv + (size_t)n * DD))[lane];
  float2 sm = {sum.x * inv + b.x, sum.y * inv + b.y};
  float2 xm = {mx.x + b.x, mx.y + b.y};
  ((float2*)(S + (size_t)n * DD))[lane] = sm;
  ((float2*)(Xm + (size_t)n * DD))[lane] = xm;
  if (lane == 0) amp[n] = logf(degf + 1.f) * 0.4f;
}

// H = [nd | S | amp*S | Xm | amp*Xm] @ Uc + Ub ; fused BN stats
__global__ __launch_bounds__(256) void u_matmul(
    const float* __restrict__ nd, const float* __restrict__ S,
    const float* __restrict__ Xm, const float* __restrict__ amp,
    const float* __restrict__ Uc, const float* __restrict__ Ub,
    float* __restrict__ H, float* __restrict__ bns, float* __restrict__ bnq) {
  __shared__ float xs[32][DD];
  __shared__ float wsW[KT][DD];
  __shared__ float ampLds[32];
  const int t = threadIdx.x;
  const int cg = t & 31;
  const int c0 = cg * 4;
  const int r0 = (t >> 5) * 4;
  const int row0 = blockIdx.x * 32;
  const float4* W4 = (const float4*)Uc;

  if (t < 32) {
    int n = row0 + t;
    ampLds[t] = (n < NN) ? amp[n] : 0.f;
  }

  float acc[4][4];
  #pragma unroll
  for (int ri = 0; ri < 4; ri++)
    #pragma unroll
    for (int cj = 0; cj < 4; cj++) acc[ri][cj] = 0.f;

  #pragma unroll
  for (int p = 0; p < 5; p++) {
    __syncthreads();   // previous panel's compute done; xs free
    if (p == 2 || p == 4) {
      // scale xs in place by amp (S -> amp*S ; Xm -> amp*Xm)
      #pragma unroll
      for (int j = 0; j < 4; j++) {
        int q = t + j * 256;
        float a = ampLds[q >> 5];
        float4 v = ((float4*)xs)[q];
        v.x *= a; v.y *= a; v.z *= a; v.w *= a;
        ((float4*)xs)[q] = v;
      }
    } else {
      const float* srcp = (p == 0) ? nd : (p == 1) ? S : Xm;
      #pragma unroll
      for (int j = 0; j < 4; j++) {
        int q = t + j * 256;
        int n = row0 + (q >> 5);
        float4 v = {0.f, 0.f, 0.f, 0.f};
        if (n < NN) v = ((const float4*)srcp)[n * 32 + (q & 31)];
        ((float4*)xs)[q] = v;
      }
    }
    float4 wreg[4];
    #pragma unroll
    for (int j = 0; j < 4; j++) wreg[j] = W4[(p * 128) * 32 + t + j * 256];

    for (int kt = 0; kt < NKT; kt++) {
      __syncthreads();   // xs/scale visible; previous wsW tile consumed
      #pragma unroll
      for (int j = 0; j < 4; j++) ((float4*)wsW)[t + j * 256] = wreg[j];
      __syncthreads();
      if (kt + 1 < NKT) {
        #pragma unroll
        for (int j = 0; j < 4; j++)
          wreg[j] = W4[(p * 128 + (kt + 1) * KT) * 32 + t + j * 256];
      }
      #pragma unroll
      for (int kg = 0; kg < KT / 4; kg++) {
        float4 w[4];
        #pragma unroll
        for (int j = 0; j < 4; j++) w[j] = *(const float4*)&wsW[kg * 4 + j][c0];
        #pragma unroll
        for (int ri = 0; ri < 4; ri++) {
          float4 x = *(const float4*)&xs[r0 + ri][kt * KT + kg * 4];
          acc[ri][0] += x.x * w[0].x + x.y * w[1].x + x.z * w[2].x + x.w * w[3].x;
          acc[ri][1] += x.x * w[0].y + x.y * w[1].y + x.z * w[2].y + x.w * w[3].y;
          acc[ri][2] += x.x * w[0].z + x.y * w[1].z + x.z * w[2].z + x.w * w[3].z;
          acc[ri][3] += x.x * w[0].w + x.y * w[1].w + x.z * w[2].w + x.w * w[3].w;
        }
      }
    }
  }

  float4 ub4 = *(const float4*)&Ub[c0];
  float sS[4] = {0.f, 0.f, 0.f, 0.f}, sQ[4] = {0.f, 0.f, 0.f, 0.f};
  #pragma unroll
  for (int ri = 0; ri < 4; ri++) {
    int n = row0 + r0 + ri;
    if (n < NN) {
      float4 h;
      h.x = acc[ri][0] + ub4.x; h.y = acc[ri][1] + ub4.y;
      h.z = acc[ri][2] + ub4.z; h.w = acc[ri][3] + ub4.w;
      ((float4*)H)[n * 32 + cg] = h;
      sS[0] += h.x; sQ[0] += h.x * h.x;
      sS[1] += h.y; sQ[1] += h.y * h.y;
      sS[2] += h.z; sQ[2] += h.z * h.z;
      sS[3] += h.w; sQ[3] += h.w * h.w;
    }
  }
  #pragma unroll
  for (int j = 0; j < 4; j++) {
    atomicAdd(bns + c0 + j, sS[j]);
    atomicAdd(bnq + c0 + j, sQ[j]);
  }
}

// out = leaky_relu( BN(H) @ mw + mb )
__global__ __launch_bounds__(256) void final_k(
    const float* __restrict__ H, const float* __restrict__ bns, const float* __restrict__ bnq,
    const float* __restrict__ gamma, const float* __restrict__ beta,
    const float* __restrict__ mw, const float* __restrict__ mb,
    float* __restrict__ out) {
  __shared__ float xs[32][DD];
  __shared__ float wsW[KT][DD];
  const int t = threadIdx.x;
  const int cg = t & 31;
  const int c0 = cg * 4;
  const int r0 = (t >> 5) * 4;
  const int row0 = blockIdx.x * 32;
  const float4* W4 = (const float4*)mw;

  const float inv = 1.f / (float)NN;
  float4 sb = ((const float4*)bns)[cg];
  float4 qb = ((const float4*)bnq)[cg];
  float4 g4 = ((const float4*)gamma)[cg];
  float4 b4 = ((const float4*)beta)[cg];
  float4 a4, o4;
  {
    float mu, var;
    mu = sb.x * inv; var = qb.x * inv - mu * mu; a4.x = g4.x * rsqrtf(var + 1e-5f); o4.x = b4.x - mu * a4.x;
    mu = sb.y * inv; var = qb.y * inv - mu * mu; a4.y = g4.y * rsqrtf(var + 1e-5f); o4.y = b4.y - mu * a4.y;
    mu = sb.z * inv; var = qb.z * inv - mu * mu; a4.z = g4.z * rsqrtf(var + 1e-5f); o4.z = b4.z - mu * a4.z;
    mu = sb.w * inv; var = qb.w * inv - mu * mu; a4.w = g4.w * rsqrtf(var + 1e-5f); o4.w = b4.w - mu * a4.w;
  }
  #pragma unroll
  for (int j = 0; j < 4; j++) {
    int q = t + j * 256;
    int n = row0 + (q >> 5);
    float4 v = {0.f, 0.f, 0.f, 0.f};
    if (n < NN) {
      float4 h = ((const float4*)H)[n * 32 + (q & 31)];   // (q&31) == cg
      v.x = a4.x * h.x + o4.x; v.y = a4.y * h.y + o4.y;
      v.z = a4.z * h.z + o4.z; v.w = a4.w * h.w + o4.w;
    }
    ((float4*)xs)[q] = v;
  }

  float acc[4][4];
  #pragma unroll
  for (int ri = 0; ri < 4; ri++)
    #pragma unroll
    for (int cj = 0; cj < 4; cj++) acc[ri][cj] = 0.f;

  float4 wreg[4];
  #pragma unroll
  for (int j = 0; j < 4; j++) wreg[j] = W4[t + j * 256];
  for (int kt = 0; kt < NKT; kt++) {
    __syncthreads();
    #pragma unroll
    for (int j = 0; j < 4; j++) ((float4*)wsW)[t + j * 256] = wreg[j];
    __syncthreads();
    if (kt + 1 < NKT) {
      #pragma unroll
      for (int j = 0; j < 4; j++) wreg[j] = W4[((kt + 1) * KT) * 32 + t + j * 256];
    }
    #pragma unroll
    for (int kg = 0; kg < KT / 4; kg++) {
      float4 w[4];
      #pragma unroll
      for (int j = 0; j < 4; j++) w[j] = *(const float4*)&wsW[kg * 4 + j][c0];
      #pragma unroll
      for (int ri = 0; ri < 4; ri++) {
        float4 x = *(const float4*)&xs[r0 + ri][kt * KT + kg * 4];
        acc[ri][0] += x.x * w[0].x + x.y * w[1].x + x.z * w[2].x + x.w * w[3].x;
        acc[ri][1] += x.x * w[0].y + x.y * w[1].y + x.z * w[2].y + x.w * w[3].y;
        acc[ri][2] += x.x * w[0].z + x.y * w[1].z + x.z * w[2].z + x.w * w[3].z;
        acc[ri][3] += x.x * w[0].w + x.y * w[1].w + x.z * w[2].w + x.w * w[3].w;
      }
    }
  }
  float4 mb4 = *(const float4*)&mb[c0];
  #pragma unroll
  for (int ri = 0; ri < 4; ri++) {
    int n = row0 + r0 + ri;
    if (n < NN) {
      float4 o;
      o.x = acc[ri][0] + mb4.x; o.y = acc[ri][1] + mb4.y;
      o.z = acc[ri][2] + mb4.z; o.w = acc[ri][3] + mb4.w;
      o.x = o.x > 0.f ? o.x : 0.01f * o.x;
      o.y = o.y > 0.f ? o.y : 0.01f * o.y;
      o.z = o.z > 0.f ? o.z : 0.01f * o.z;
      o.w = o.w > 0.f ? o.w : 0.01f * o.w;
      ((float4*)out)[n * 32 + cg] = o;
    }
  }
}

extern "C" void kernel_launch(void* const* d_in, const int* in_sizes, int n_in,
                              void* d_out, int out_size, void* d_ws, size_t ws_size,
                              hipStream_t stream) {
  const float* nd    = (const float*)d_in[0];
  const float* Mw    = (const float*)d_in[1];
  const float* Mb    = (const float*)d_in[2];
  const float* Uw    = (const float*)d_in[3];
  const float* Ub    = (const float*)d_in[4];
  const float* gamma = (const float*)d_in[5];
  const float* beta  = (const float*)d_in[6];
  const float* mixw  = (const float*)d_in[7];
  const float* mixb  = (const float*)d_in[8];
  const int* src = (const int*)d_in[9];
  const int* dst = (const int*)d_in[10];
  float* out = (float*)d_out;

  float* ws  = (float*)d_ws;
  float* A   = ws;
  float* Bv  = A + NN * DD;
  float* S   = Bv + NN * DD;
  float* Xm  = S + NN * DD;
  float* H   = Xm + NN * DD;
  float* amp = H + NN * DD;
  float* bns = amp + NN;
  float* bnq = bns + DD;
  float* Uc  = bnq + DD;
  unsigned int* cnt    = (unsigned int*)(Uc + 5 * DD * DD);
  unsigned int* off    = cnt + NN;
  unsigned int* cursor = off + NN + 1;
  unsigned int* eidx   = cursor + NN;

  const int MB = (NN + 31) / 32;  // 1563 row-blocks
  combine_w<<<(5 * DD * DD + 255) / 256, 256, 0, stream>>>(Uw, Uc);
  prep_ab<<<MB, 256, 0, stream>>>(nd, Mw, Mb, A, Bv);
  init_small<<<(NN + 255) / 256, 256, 0, stream>>>(cnt, bns, bnq);
  deg_count<<<(EE + 255) / 256, 256, 0, stream>>>(dst, cnt);
  scan_k<<<1, 1024, 0, stream>>>(cnt, off, cursor);
  fill_k<<<(EE + 255) / 256, 256, 0, stream>>>(src, dst, cursor, eidx);
  aggregate<<<(NN + 3) / 4, 256, 0, stream>>>(A, Bv, off, eidx, S, Xm, amp);
  u_matmul<<<MB, 256, 0, stream>>>(nd, S, Xm, amp, Uc, Ub, H, bns, bnq);
  final_k<<<MB, 256, 0, stream>>>(H, bns, bnq, gamma, beta, mixw, mixb, out);
}

// Round 6
// 1711.052 us; speedup vs baseline: 1.4860x; 1.1610x over previous
//
#include <hip/hip_runtime.h>

#define NN 50000
#define EE 800000
#define DD 128

// Uc = [W0 ; W1+W3 ; W4+W6 ; W2 ; W5]  (640 x 128), panel order: nd, S, amp*S, Xm, amp*Xm
__global__ __launch_bounds__(256) void combine_w(
    const float* __restrict__ Uw, float* __restrict__ Uc) {
  int i = blockIdx.x * 256 + threadIdx.x;
  if (i >= 5 * DD * DD) return;
  int p = i / (DD * DD);
  int rc = i - p * (DD * DD);
  float v;
  switch (p) {
    case 0: v = Uw[rc]; break;
    case 1: v = Uw[128 * DD + rc] + Uw[384 * DD + rc]; break;
    case 2: v = Uw[512 * DD + rc] + Uw[768 * DD + rc]; break;
    case 3: v = Uw[256 * DD + rc]; break;
    default: v = Uw[640 * DD + rc]; break;
  }
  Uc[i] = v;
}

// ---- prep_ab : A = nd@Mw[0:128] ; B = nd@Mw[128:256] + Mb ----
// 256 thr, 32 rows/block, 4x4 thread tile, full weight panel in LDS, rolled k-loop.
__global__ __launch_bounds__(256) void prep_ab(
    const float* __restrict__ nd, const float* __restrict__ Mw,
    const float* __restrict__ Mb, float* __restrict__ A, float* __restrict__ B) {
  __shared__ float xs[32][DD];   // 16 KB
  __shared__ float wp[DD][DD];   // 64 KB
  const int t = threadIdx.x;
  const int cg = t & 31;
  const int c0 = cg * 4;
  const int r0 = (t >> 5) * 4;
  const int row0 = blockIdx.x * 32;
  const float4* W4 = (const float4*)Mw;

  #pragma unroll
  for (int j = 0; j < 4; j++) {
    int q = t + j * 256;
    int n = row0 + (q >> 5);
    float4 v = {0.f, 0.f, 0.f, 0.f};
    if (n < NN) v = ((const float4*)nd)[n * 32 + (q & 31)];
    ((float4*)xs)[q] = v;
  }
  float4 mb4 = *(const float4*)&Mb[c0];

  #pragma unroll 1
  for (int pass = 0; pass < 2; pass++) {
    __syncthreads();   // xs writes (pass0) / previous compute done
    #pragma unroll
    for (int j = 0; j < 16; j++)
      ((float4*)wp)[t + j * 256] = W4[pass * 4096 + t + j * 256];
    __syncthreads();

    float acc[4][4];
    #pragma unroll
    for (int ri = 0; ri < 4; ri++)
      #pragma unroll
      for (int cj = 0; cj < 4; cj++) acc[ri][cj] = 0.f;

    #pragma unroll 1
    for (int kg = 0; kg < 32; kg++) {
      float4 w0 = *(const float4*)&wp[kg * 4 + 0][c0];
      float4 w1 = *(const float4*)&wp[kg * 4 + 1][c0];
      float4 w2 = *(const float4*)&wp[kg * 4 + 2][c0];
      float4 w3 = *(const float4*)&wp[kg * 4 + 3][c0];
      #pragma unroll
      for (int ri = 0; ri < 4; ri++) {
        float4 x = *(const float4*)&xs[r0 + ri][kg * 4];
        acc[ri][0] += x.x * w0.x + x.y * w1.x + x.z * w2.x + x.w * w3.x;
        acc[ri][1] += x.x * w0.y + x.y * w1.y + x.z * w2.y + x.w * w3.y;
        acc[ri][2] += x.x * w0.z + x.y * w1.z + x.z * w2.z + x.w * w3.z;
        acc[ri][3] += x.x * w0.w + x.y * w1.w + x.z * w2.w + x.w * w3.w;
      }
    }
    float* dstp = pass ? B : A;
    #pragma unroll
    for (int ri = 0; ri < 4; ri++) {
      int n = row0 + r0 + ri;
      if (n < NN) {
        float4 o;
        o.x = acc[ri][0]; o.y = acc[ri][1]; o.z = acc[ri][2]; o.w = acc[ri][3];
        if (pass) { o.x += mb4.x; o.y += mb4.y; o.z += mb4.z; o.w += mb4.w; }
        ((float4*)dstp)[n * 32 + cg] = o;
      }
    }
  }
}

__global__ __launch_bounds__(256) void init_small(
    unsigned int* __restrict__ cnt, float* __restrict__ bns, float* __restrict__ bnq) {
  int i = blockIdx.x * 256 + threadIdx.x;
  if (i < NN) cnt[i] = 0u;
  if (i < DD) { bns[i] = 0.f; bnq[i] = 0.f; }
}

__global__ __launch_bounds__(256) void deg_count(
    const int* __restrict__ dst, unsigned int* __restrict__ cnt) {
  int e = blockIdx.x * 256 + threadIdx.x;
  if (e < EE) atomicAdd(&cnt[dst[e]], 1u);
}

__global__ __launch_bounds__(1024) void scan_k(
    const unsigned int* __restrict__ cnt, unsigned int* __restrict__ off,
    unsigned int* __restrict__ cursor) {
  __shared__ unsigned int part[1024];
  const int t = threadIdx.x;
  const int CH = (NN + 1023) / 1024;
  int beg = t * CH, end = beg + CH;
  if (end > NN) end = NN;
  unsigned int s = 0;
  for (int i = beg; i < end; i++) s += cnt[i];
  part[t] = s;
  __syncthreads();
  for (int d = 1; d < 1024; d <<= 1) {
    unsigned int v = (t >= d) ? part[t - d] : 0u;
    __syncthreads();
    part[t] += v;
    __syncthreads();
  }
  unsigned int run = part[t] - s;
  for (int i = beg; i < end; i++) {
    off[i] = run; cursor[i] = run; run += cnt[i];
  }
  if (t == 0) off[NN] = EE;
}

__global__ __launch_bounds__(256) void fill_k(
    const int* __restrict__ src, const int* __restrict__ dst,
    unsigned int* __restrict__ cursor, unsigned int* __restrict__ eidx) {
  int e = blockIdx.x * 256 + threadIdx.x;
  if (e < EE) {
    unsigned int p = atomicAdd(&cursor[dst[e]], 1u);
    eidx[p] = (unsigned int)src[e];
  }
}

// gather-aggregate: one wave per node
__global__ __launch_bounds__(256) void aggregate(
    const float* __restrict__ A, const float* __restrict__ Bv,
    const unsigned int* __restrict__ off, const unsigned int* __restrict__ eidx,
    float* __restrict__ S, float* __restrict__ Xm, float* __restrict__ amp) {
  int wave = threadIdx.x >> 6, lane = threadIdx.x & 63;
  int n = blockIdx.x * 4 + wave;
  if (n >= NN) return;
  unsigned int b0 = off[n], b1 = off[n + 1];
  float2 sum = ((const float2*)(A + (size_t)n * DD))[lane];
  float2 mx = sum;
  for (unsigned int j0 = b0; j0 < b1; j0 += 64) {
    int m = (int)min(64u, b1 - j0);
    int myi = (lane < m) ? (int)eidx[j0 + lane] : 0;
    for (int j = 0; j < m; j++) {
      int sN = __shfl(myi, j);
      float2 a = ((const float2*)(A + (size_t)sN * DD))[lane];
      sum.x += a.x; sum.y += a.y;
      mx.x = fmaxf(mx.x, a.x); mx.y = fmaxf(mx.y, a.y);
    }
  }
  float degf = (float)(b1 - b0) + 1.f;
  float inv = 1.f / degf;
  float2 b = ((const float2*)(Bv + (size_t)n * DD))[lane];
  float2 sm = {sum.x * inv + b.x, sum.y * inv + b.y};
  float2 xm = {mx.x + b.x, mx.y + b.y};
  ((float2*)(S + (size_t)n * DD))[lane] = sm;
  ((float2*)(Xm + (size_t)n * DD))[lane] = xm;
  if (lane == 0) amp[n] = logf(degf + 1.f) * 0.4f;
}

// H = [nd | S | amp*S | Xm | amp*Xm] @ Uc + Ub ; fused BN stats
__global__ __launch_bounds__(256) void u_matmul(
    const float* __restrict__ nd, const float* __restrict__ S,
    const float* __restrict__ Xm, const float* __restrict__ amp,
    const float* __restrict__ Uc, const float* __restrict__ Ub,
    float* __restrict__ H, float* __restrict__ bns, float* __restrict__ bnq) {
  __shared__ float xs[32][DD];   // 16 KB
  __shared__ float wp[DD][DD];   // 64 KB
  __shared__ float ampLds[32];
  const int t = threadIdx.x;
  const int cg = t & 31;
  const int c0 = cg * 4;
  const int r0 = (t >> 5) * 4;
  const int row0 = blockIdx.x * 32;
  const float4* W4 = (const float4*)Uc;

  if (t < 32) {
    int n = row0 + t;
    ampLds[t] = (n < NN) ? amp[n] : 0.f;
  }

  float acc[4][4];
  #pragma unroll
  for (int ri = 0; ri < 4; ri++)
    #pragma unroll
    for (int cj = 0; cj < 4; cj++) acc[ri][cj] = 0.f;

  #pragma unroll 1
  for (int p = 0; p < 5; p++) {
    __syncthreads();   // previous panel's compute done; xs/wp free
    if (p == 2 || p == 4) {
      #pragma unroll
      for (int j = 0; j < 4; j++) {
        int q = t + j * 256;
        float a = ampLds[q >> 5];
        float4 v = ((float4*)xs)[q];
        v.x *= a; v.y *= a; v.z *= a; v.w *= a;
        ((float4*)xs)[q] = v;
      }
    } else {
      const float* srcp = (p == 0) ? nd : (p == 1) ? S : Xm;
      #pragma unroll
      for (int j = 0; j < 4; j++) {
        int q = t + j * 256;
        int n = row0 + (q >> 5);
        float4 v = {0.f, 0.f, 0.f, 0.f};
        if (n < NN) v = ((const float4*)srcp)[n * 32 + (q & 31)];
        ((float4*)xs)[q] = v;
      }
    }
    #pragma unroll
    for (int j = 0; j < 16; j++)
      ((float4*)wp)[t + j * 256] = W4[p * 4096 + t + j * 256];
    __syncthreads();

    #pragma unroll 1
    for (int kg = 0; kg < 32; kg++) {
      float4 w0 = *(const float4*)&wp[kg * 4 + 0][c0];
      float4 w1 = *(const float4*)&wp[kg * 4 + 1][c0];
      float4 w2 = *(const float4*)&wp[kg * 4 + 2][c0];
      float4 w3 = *(const float4*)&wp[kg * 4 + 3][c0];
      #pragma unroll
      for (int ri = 0; ri < 4; ri++) {
        float4 x = *(const float4*)&xs[r0 + ri][kg * 4];
        acc[ri][0] += x.x * w0.x + x.y * w1.x + x.z * w2.x + x.w * w3.x;
        acc[ri][1] += x.x * w0.y + x.y * w1.y + x.z * w2.y + x.w * w3.y;
        acc[ri][2] += x.x * w0.z + x.y * w1.z + x.z * w2.z + x.w * w3.z;
        acc[ri][3] += x.x * w0.w + x.y * w1.w + x.z * w2.w + x.w * w3.w;
      }
    }
  }

  float4 ub4 = *(const float4*)&Ub[c0];
  float sS[4] = {0.f, 0.f, 0.f, 0.f}, sQ[4] = {0.f, 0.f, 0.f, 0.f};
  #pragma unroll
  for (int ri = 0; ri < 4; ri++) {
    int n = row0 + r0 + ri;
    if (n < NN) {
      float4 h;
      h.x = acc[ri][0] + ub4.x; h.y = acc[ri][1] + ub4.y;
      h.z = acc[ri][2] + ub4.z; h.w = acc[ri][3] + ub4.w;
      ((float4*)H)[n * 32 + cg] = h;
      sS[0] += h.x; sQ[0] += h.x * h.x;
      sS[1] += h.y; sQ[1] += h.y * h.y;
      sS[2] += h.z; sQ[2] += h.z * h.z;
      sS[3] += h.w; sQ[3] += h.w * h.w;
    }
  }
  #pragma unroll
  for (int j = 0; j < 4; j++) {
    atomicAdd(bns + c0 + j, sS[j]);
    atomicAdd(bnq + c0 + j, sQ[j]);
  }
}

// out = leaky_relu( BN(H) @ mw + mb )
__global__ __launch_bounds__(256) void final_k(
    const float* __restrict__ H, const float* __restrict__ bns, const float* __restrict__ bnq,
    const float* __restrict__ gamma, const float* __restrict__ beta,
    const float* __restrict__ mw, const float* __restrict__ mb,
    float* __restrict__ out) {
  __shared__ float xs[32][DD];
  __shared__ float wp[DD][DD];
  const int t = threadIdx.x;
  const int cg = t & 31;
  const int c0 = cg * 4;
  const int r0 = (t >> 5) * 4;
  const int row0 = blockIdx.x * 32;
  const float4* W4 = (const float4*)mw;

  const float inv = 1.f / (float)NN;
  float4 sb = ((const float4*)bns)[cg];
  float4 qb = ((const float4*)bnq)[cg];
  float4 g4 = ((const float4*)gamma)[cg];
  float4 b4 = ((const float4*)beta)[cg];
  float4 a4, o4;
  {
    float mu, var;
    mu = sb.x * inv; var = qb.x * inv - mu * mu; a4.x = g4.x * rsqrtf(var + 1e-5f); o4.x = b4.x - mu * a4.x;
    mu = sb.y * inv; var = qb.y * inv - mu * mu; a4.y = g4.y * rsqrtf(var + 1e-5f); o4.y = b4.y - mu * a4.y;
    mu = sb.z * inv; var = qb.z * inv - mu * mu; a4.z = g4.z * rsqrtf(var + 1e-5f); o4.z = b4.z - mu * a4.z;
    mu = sb.w * inv; var = qb.w * inv - mu * mu; a4.w = g4.w * rsqrtf(var + 1e-5f); o4.w = b4.w - mu * a4.w;
  }
  #pragma unroll
  for (int j = 0; j < 4; j++) {
    int q = t + j * 256;
    int n = row0 + (q >> 5);
    float4 v = {0.f, 0.f, 0.f, 0.f};
    if (n < NN) {
      float4 h = ((const float4*)H)[n * 32 + (q & 31)];
      v.x = a4.x * h.x + o4.x; v.y = a4.y * h.y + o4.y;
      v.z = a4.z * h.z + o4.z; v.w = a4.w * h.w + o4.w;
    }
    ((float4*)xs)[q] = v;
  }
  #pragma unroll
  for (int j = 0; j < 16; j++)
    ((float4*)wp)[t + j * 256] = W4[t + j * 256];
  __syncthreads();

  float acc[4][4];
  #pragma unroll
  for (int ri = 0; ri < 4; ri++)
    #pragma unroll
    for (int cj = 0; cj < 4; cj++) acc[ri][cj] = 0.f;

  #pragma unroll 1
  for (int kg = 0; kg < 32; kg++) {
    float4 w0 = *(const float4*)&wp[kg * 4 + 0][c0];
    float4 w1 = *(const float4*)&wp[kg * 4 + 1][c0];
    float4 w2 = *(const float4*)&wp[kg * 4 + 2][c0];
    float4 w3 = *(const float4*)&wp[kg * 4 + 3][c0];
    #pragma unroll
    for (int ri = 0; ri < 4; ri++) {
      float4 x = *(const float4*)&xs[r0 + ri][kg * 4];
      acc[ri][0] += x.x * w0.x + x.y * w1.x + x.z * w2.x + x.w * w3.x;
      acc[ri][1] += x.x * w0.y + x.y * w1.y + x.z * w2.y + x.w * w3.y;
      acc[ri][2] += x.x * w0.z + x.y * w1.z + x.z * w2.z + x.w * w3.z;
      acc[ri][3] += x.x * w0.w + x.y * w1.w + x.z * w2.w + x.w * w3.w;
    }
  }
  float4 mb4 = *(const float4*)&mb[c0];
  #pragma unroll
  for (int ri = 0; ri < 4; ri++) {
    int n = row0 + r0 + ri;
    if (n < NN) {
      float4 o;
      o.x = acc[ri][0] + mb4.x; o.y = acc[ri][1] + mb4.y;
      o.z = acc[ri][2] + mb4.z; o.w = acc[ri][3] + mb4.w;
      o.x = o.x > 0.f ? o.x : 0.01f * o.x;
      o.y = o.y > 0.f ? o.y : 0.01f * o.y;
      o.z = o.z > 0.f ? o.z : 0.01f * o.z;
      o.w = o.w > 0.f ? o.w : 0.01f * o.w;
      ((float4*)out)[n * 32 + cg] = o;
    }
  }
}

extern "C" void kernel_launch(void* const* d_in, const int* in_sizes, int n_in,
                              void* d_out, int out_size, void* d_ws, size_t ws_size,
                              hipStream_t stream) {
  const float* nd    = (const float*)d_in[0];
  const float* Mw    = (const float*)d_in[1];
  const float* Mb    = (const float*)d_in[2];
  const float* Uw    = (const float*)d_in[3];
  const float* Ub    = (const float*)d_in[4];
  const float* gamma = (const float*)d_in[5];
  const float* beta  = (const float*)d_in[6];
  const float* mixw  = (const float*)d_in[7];
  const float* mixb  = (const float*)d_in[8];
  const int* src = (const int*)d_in[9];
  const int* dst = (const int*)d_in[10];
  float* out = (float*)d_out;

  float* ws  = (float*)d_ws;
  float* A   = ws;
  float* Bv  = A + NN * DD;
  float* S   = Bv + NN * DD;
  float* Xm  = S + NN * DD;
  float* H   = Xm + NN * DD;
  float* amp = H + NN * DD;
  float* bns = amp + NN;
  float* bnq = bns + DD;
  float* Uc  = bnq + DD;
  unsigned int* cnt    = (unsigned int*)(Uc + 5 * DD * DD);
  unsigned int* off    = cnt + NN;
  unsigned int* cursor = off + NN + 1;
  unsigned int* eidx   = cursor + NN;

  const int MB = (NN + 31) / 32;  // 1563 row-blocks
  combine_w<<<(5 * DD * DD + 255) / 256, 256, 0, stream>>>(Uw, Uc);
  prep_ab<<<MB, 256, 0, stream>>>(nd, Mw, Mb, A, Bv);
  init_small<<<(NN + 255) / 256, 256, 0, stream>>>(cnt, bns, bnq);
  deg_count<<<(EE + 255) / 256, 256, 0, stream>>>(dst, cnt);
  scan_k<<<1, 1024, 0, stream>>>(cnt, off, cursor);
  fill_k<<<(EE + 255) / 256, 256, 0, stream>>>(src, dst, cursor, eidx);
  aggregate<<<(NN + 3) / 4, 256, 0, stream>>>(A, Bv, off, eidx, S, Xm, amp);
  u_matmul<<<MB, 256, 0, stream>>>(nd, S, Xm, amp, Uc, Ub, H, bns, bnq);
  final_k<<<MB, 256, 0, stream>>>(H, bns, bnq, gamma, beta, mixw, mixb, out);
}

// Round 7
// 512.509 us; speedup vs baseline: 4.9612x; 3.3386x over previous
//
#include <hip/hip_runtime.h>
#include <hip/hip_bf16.h>

#define NN 50000
#define EE 800000
#define DD 128

typedef short bf8 __attribute__((ext_vector_type(8)));     // 8 bf16 bit-patterns (4 VGPR)
typedef float f32x4 __attribute__((ext_vector_type(4)));

__device__ __forceinline__ unsigned short f2b(float f) {
  __hip_bfloat16 h = __float2bfloat16(f);
  return *reinterpret_cast<unsigned short*>(&h);
}

// build A-fragment: 8 consecutive k-floats from p, scaled, bf16-converted
__device__ __forceinline__ bf8 mk_a(const float* __restrict__ p, float sc) {
  float4 x0 = *(const float4*)p;
  float4 x1 = *(const float4*)(p + 4);
  bf8 a;
  a[0] = (short)f2b(x0.x * sc); a[1] = (short)f2b(x0.y * sc);
  a[2] = (short)f2b(x0.z * sc); a[3] = (short)f2b(x0.w * sc);
  a[4] = (short)f2b(x1.x * sc); a[5] = (short)f2b(x1.y * sc);
  a[6] = (short)f2b(x1.z * sc); a[7] = (short)f2b(x1.w * sc);
  return a;
}

// ---------- weight packing into MFMA B-fragment order (bf16 bits) ----------
// out[((kt*N16+ct)*64+l)*8+j] = W(k = kt*32 + (l>>4)*8 + j , c = ct*16 + (l&15))

// prep weights: N=256 ([Mw_top | Mw_bot]), K=128  -> 32768 elems
__global__ __launch_bounds__(256) void pack_prep(const float* __restrict__ Mw,
                                                 unsigned short* __restrict__ Mp) {
  int gid = blockIdx.x * 256 + threadIdx.x;
  if (gid >= 32768) return;
  int j = gid & 7, l = (gid >> 3) & 63, ct = (gid >> 9) & 15, kt = gid >> 13;
  int k = kt * 32 + ((l >> 4) << 3) + j;
  int c = ct * 16 + (l & 15);
  float v = (c < 128) ? Mw[k * DD + c] : Mw[(128 + k) * DD + (c - 128)];
  Mp[gid] = f2b(v);
}

// U weights combined: K=640 panels [W0; W1+W3; W4+W6; W2; W5], N=128 -> 81920 elems
__global__ __launch_bounds__(256) void pack_u(const float* __restrict__ Uw,
                                              unsigned short* __restrict__ Up) {
  int gid = blockIdx.x * 256 + threadIdx.x;
  if (gid >= 81920) return;
  int j = gid & 7, l = (gid >> 3) & 63, ct = (gid >> 9) & 7, kt = gid >> 12;
  int k = kt * 32 + ((l >> 4) << 3) + j;
  int p = k >> 7, kk = k & 127;
  int c = ct * 16 + (l & 15);
  float v;
  switch (p) {
    case 0: v = Uw[kk * DD + c]; break;
    case 1: v = Uw[(128 + kk) * DD + c] + Uw[(384 + kk) * DD + c]; break;
    case 2: v = Uw[(512 + kk) * DD + c] + Uw[(768 + kk) * DD + c]; break;
    case 3: v = Uw[(256 + kk) * DD + c]; break;
    default: v = Uw[(640 + kk) * DD + c]; break;
  }
  Up[gid] = f2b(v);
}

// mix weights: K=128, N=128 -> 16384 elems
__global__ __launch_bounds__(256) void pack_mix(const float* __restrict__ Mixw,
                                                unsigned short* __restrict__ Xp) {
  int gid = blockIdx.x * 256 + threadIdx.x;
  if (gid >= 16384) return;
  int j = gid & 7, l = (gid >> 3) & 63, ct = (gid >> 9) & 7, kt = gid >> 12;
  int k = kt * 32 + ((l >> 4) << 3) + j;
  int c = ct * 16 + (l & 15);
  Xp[gid] = f2b(Mixw[k * DD + c]);
}

// ---------- gemm_prep : A = nd@Mw_top ; Bv = nd@Mw_bot + Mb ----------
// 4 waves: (w&1) row strip, (w>>1) output half. 32 rows/block.
__global__ __launch_bounds__(256) void gemm_prep(
    const float* __restrict__ nd, const unsigned short* __restrict__ Mp,
    const float* __restrict__ Mb, float* __restrict__ A, float* __restrict__ Bv) {
  const int w = threadIdx.x >> 6, l = threadIdx.x & 63;
  const int half = w >> 1;
  const int row0 = blockIdx.x * 32 + (w & 1) * 16;
  const int rc = min(row0 + (l & 15), NN - 1);
  const int ko = (l >> 4) * 8;
  const bf8* B8 = (const bf8*)Mp;
  f32x4 zero = {0.f, 0.f, 0.f, 0.f};
  f32x4 acc[8];
  #pragma unroll
  for (int i = 0; i < 8; i++) acc[i] = zero;
  #pragma unroll
  for (int ks = 0; ks < 4; ks++) {
    bf8 a = mk_a(nd + (size_t)rc * DD + ks * 32 + ko, 1.f);
    #pragma unroll
    for (int ct = 0; ct < 8; ct++) {
      bf8 b = B8[(ks * 16 + half * 8 + ct) * 64 + l];
      acc[ct] = __builtin_amdgcn_mfma_f32_16x16x32_bf16(a, b, acc[ct], 0, 0, 0);
    }
  }
  const int rb = row0 + (l >> 4) * 4;
  float* outp = half ? Bv : A;
  #pragma unroll
  for (int ct = 0; ct < 8; ct++) {
    int c = ct * 16 + (l & 15);
    float bias = half ? Mb[c] : 0.f;
    #pragma unroll
    for (int jj = 0; jj < 4; jj++) {
      int rr = rb + jj;
      if (rr < NN) outp[(size_t)rr * DD + c] = acc[ct][jj] + bias;
    }
  }
}

__global__ __launch_bounds__(256) void init_small(
    unsigned int* __restrict__ cnt, float* __restrict__ bns, float* __restrict__ bnq) {
  int i = blockIdx.x * 256 + threadIdx.x;
  if (i < NN) cnt[i] = 0u;
  if (i < DD) { bns[i] = 0.f; bnq[i] = 0.f; }
}

__global__ __launch_bounds__(256) void deg_count(
    const int* __restrict__ dst, unsigned int* __restrict__ cnt) {
  int e = blockIdx.x * 256 + threadIdx.x;
  if (e < EE) atomicAdd(&cnt[dst[e]], 1u);
}

__global__ __launch_bounds__(1024) void scan_k(
    const unsigned int* __restrict__ cnt, unsigned int* __restrict__ off,
    unsigned int* __restrict__ cursor) {
  __shared__ unsigned int part[1024];
  const int t = threadIdx.x;
  const int CH = (NN + 1023) / 1024;
  int beg = t * CH, end = beg + CH;
  if (end > NN) end = NN;
  unsigned int s = 0;
  for (int i = beg; i < end; i++) s += cnt[i];
  part[t] = s;
  __syncthreads();
  for (int d = 1; d < 1024; d <<= 1) {
    unsigned int v = (t >= d) ? part[t - d] : 0u;
    __syncthreads();
    part[t] += v;
    __syncthreads();
  }
  unsigned int run = part[t] - s;
  for (int i = beg; i < end; i++) {
    off[i] = run; cursor[i] = run; run += cnt[i];
  }
  if (t == 0) off[NN] = EE;
}

__global__ __launch_bounds__(256) void fill_k(
    const int* __restrict__ src, const int* __restrict__ dst,
    unsigned int* __restrict__ cursor, unsigned int* __restrict__ eidx) {
  int e = blockIdx.x * 256 + threadIdx.x;
  if (e < EE) {
    unsigned int p = atomicAdd(&cursor[dst[e]], 1u);
    eidx[p] = (unsigned int)src[e];
  }
}

// gather-aggregate: one wave per node
__global__ __launch_bounds__(256) void aggregate(
    const float* __restrict__ A, const float* __restrict__ Bv,
    const unsigned int* __restrict__ off, const unsigned int* __restrict__ eidx,
    float* __restrict__ S, float* __restrict__ Xm, float* __restrict__ amp) {
  int wave = threadIdx.x >> 6, lane = threadIdx.x & 63;
  int n = blockIdx.x * 4 + wave;
  if (n >= NN) return;
  unsigned int b0 = off[n], b1 = off[n + 1];
  float2 sum = ((const float2*)(A + (size_t)n * DD))[lane];
  float2 mx = sum;
  for (unsigned int j0 = b0; j0 < b1; j0 += 64) {
    int m = (int)min(64u, b1 - j0);
    int myi = (lane < m) ? (int)eidx[j0 + lane] : 0;
    for (int j = 0; j < m; j++) {
      int sN = __shfl(myi, j);
      float2 a = ((const float2*)(A + (size_t)sN * DD))[lane];
      sum.x += a.x; sum.y += a.y;
      mx.x = fmaxf(mx.x, a.x); mx.y = fmaxf(mx.y, a.y);
    }
  }
  float degf = (float)(b1 - b0) + 1.f;
  float inv = 1.f / degf;
  float2 b = ((const float2*)(Bv + (size_t)n * DD))[lane];
  float2 sm = {sum.x * inv + b.x, sum.y * inv + b.y};
  float2 xm = {mx.x + b.x, mx.y + b.y};
  ((float2*)(S + (size_t)n * DD))[lane] = sm;
  ((float2*)(Xm + (size_t)n * DD))[lane] = xm;
  if (lane == 0) amp[n] = logf(degf + 1.f) * 0.4f;
}

// ---------- gemm_u : H = [nd|S|amp*S|Xm|amp*Xm] @ Uc + Ub ----------
// 4 waves x 16 rows = 64 rows/block, N=128 (8 col-tiles/wave), K=640
__global__ __launch_bounds__(256) void gemm_u(
    const float* __restrict__ nd, const float* __restrict__ S, const float* __restrict__ Xm,
    const float* __restrict__ amp, const unsigned short* __restrict__ Up,
    const float* __restrict__ Ub, float* __restrict__ H) {
  const int w = threadIdx.x >> 6, l = threadIdx.x & 63;
  const int row0 = blockIdx.x * 64 + w * 16;
  const int rc = min(row0 + (l & 15), NN - 1);
  const int ko = (l >> 4) * 8;
  const float av = amp[rc];
  const bf8* B8 = (const bf8*)Up;
  f32x4 zero = {0.f, 0.f, 0.f, 0.f};
  f32x4 acc[8];
  #pragma unroll
  for (int i = 0; i < 8; i++) acc[i] = zero;

  #pragma unroll 1
  for (int p = 0; p < 5; p++) {
    const float* sp = (p == 0) ? nd : (p < 3) ? S : Xm;
    const float sc = (p == 2 || p == 4) ? av : 1.f;
    const float* base = sp + (size_t)rc * DD + ko;
    #pragma unroll
    for (int q = 0; q < 4; q++) {
      bf8 a = mk_a(base + q * 32, sc);
      const int ks = p * 4 + q;
      #pragma unroll
      for (int ct = 0; ct < 8; ct++) {
        bf8 b = B8[(ks * 8 + ct) * 64 + l];
        acc[ct] = __builtin_amdgcn_mfma_f32_16x16x32_bf16(a, b, acc[ct], 0, 0, 0);
      }
    }
  }
  const int rb = row0 + (l >> 4) * 4;
  #pragma unroll
  for (int ct = 0; ct < 8; ct++) {
    int c = ct * 16 + (l & 15);
    float ub = Ub[c];
    #pragma unroll
    for (int jj = 0; jj < 4; jj++) {
      int rr = rb + jj;
      if (rr < NN) H[(size_t)rr * DD + c] = acc[ct][jj] + ub;
    }
  }
}

__global__ __launch_bounds__(256) void bn_stats(
    const float* __restrict__ H, float* __restrict__ bns, float* __restrict__ bnq) {
  int c = threadIdx.x & 127, g = threadIdx.x >> 7;
  float s = 0.f, q = 0.f;
  for (int n = blockIdx.x * 2 + g; n < NN; n += gridDim.x * 2) {
    float v = H[n * DD + c];
    s += v; q += v * v;
  }
  atomicAdd(bns + c, s);
  atomicAdd(bnq + c, q);
}

__global__ __launch_bounds__(128) void bn_finalize(
    const float* __restrict__ bns, const float* __restrict__ bnq,
    const float* __restrict__ gamma, const float* __restrict__ beta,
    float* __restrict__ bnA, float* __restrict__ bnO) {
  int c = threadIdx.x;
  float mu = bns[c] * (1.f / NN);
  float var = bnq[c] * (1.f / NN) - mu * mu;
  float a = gamma[c] * rsqrtf(var + 1e-5f);
  bnA[c] = a;
  bnO[c] = beta[c] - mu * a;
}

// ---------- gemm_final : out = leaky( (H*bnA+bnO) @ mixw + mixb ) ----------
__global__ __launch_bounds__(256) void gemm_final(
    const float* __restrict__ H, const float* __restrict__ bnA, const float* __restrict__ bnO,
    const unsigned short* __restrict__ Xp, const float* __restrict__ mixb,
    float* __restrict__ out) {
  const int w = threadIdx.x >> 6, l = threadIdx.x & 63;
  const int row0 = blockIdx.x * 64 + w * 16;
  const int rc = min(row0 + (l & 15), NN - 1);
  const int ko = (l >> 4) * 8;
  const bf8* B8 = (const bf8*)Xp;
  f32x4 zero = {0.f, 0.f, 0.f, 0.f};
  f32x4 acc[8];
  #pragma unroll
  for (int i = 0; i < 8; i++) acc[i] = zero;

  #pragma unroll
  for (int ks = 0; ks < 4; ks++) {
    const float* p = H + (size_t)rc * DD + ks * 32 + ko;
    float4 x0 = *(const float4*)p;
    float4 x1 = *(const float4*)(p + 4);
    float4 a0 = *(const float4*)(bnA + ks * 32 + ko);
    float4 a1 = *(const float4*)(bnA + ks * 32 + ko + 4);
    float4 o0 = *(const float4*)(bnO + ks * 32 + ko);
    float4 o1 = *(const float4*)(bnO + ks * 32 + ko + 4);
    bf8 a;
    a[0] = (short)f2b(x0.x * a0.x + o0.x); a[1] = (short)f2b(x0.y * a0.y + o0.y);
    a[2] = (short)f2b(x0.z * a0.z + o0.z); a[3] = (short)f2b(x0.w * a0.w + o0.w);
    a[4] = (short)f2b(x1.x * a1.x + o1.x); a[5] = (short)f2b(x1.y * a1.y + o1.y);
    a[6] = (short)f2b(x1.z * a1.z + o1.z); a[7] = (short)f2b(x1.w * a1.w + o1.w);
    #pragma unroll
    for (int ct = 0; ct < 8; ct++) {
      bf8 b = B8[(ks * 8 + ct) * 64 + l];
      acc[ct] = __builtin_amdgcn_mfma_f32_16x16x32_bf16(a, b, acc[ct], 0, 0, 0);
    }
  }
  const int rb = row0 + (l >> 4) * 4;
  #pragma unroll
  for (int ct = 0; ct < 8; ct++) {
    int c = ct * 16 + (l & 15);
    float mbv = mixb[c];
    #pragma unroll
    for (int jj = 0; jj < 4; jj++) {
      int rr = rb + jj;
      if (rr < NN) {
        float o = acc[ct][jj] + mbv;
        o = o > 0.f ? o : 0.01f * o;
        out[(size_t)rr * DD + c] = o;
      }
    }
  }
}

extern "C" void kernel_launch(void* const* d_in, const int* in_sizes, int n_in,
                              void* d_out, int out_size, void* d_ws, size_t ws_size,
                              hipStream_t stream) {
  const float* nd    = (const float*)d_in[0];
  const float* Mw    = (const float*)d_in[1];
  const float* Mb    = (const float*)d_in[2];
  const float* Uw    = (const float*)d_in[3];
  const float* Ub    = (const float*)d_in[4];
  const float* gamma = (const float*)d_in[5];
  const float* beta  = (const float*)d_in[6];
  const float* mixw  = (const float*)d_in[7];
  const float* mixb  = (const float*)d_in[8];
  const int* src = (const int*)d_in[9];
  const int* dst = (const int*)d_in[10];
  float* out = (float*)d_out;

  float* ws  = (float*)d_ws;
  float* A   = ws;
  float* Bv  = A + (size_t)NN * DD;
  float* S   = Bv + (size_t)NN * DD;
  float* Xm  = S + (size_t)NN * DD;
  float* H   = Xm + (size_t)NN * DD;
  float* amp = H + (size_t)NN * DD;
  float* bns = amp + NN;
  float* bnq = bns + DD;
  float* bnA = bnq + DD;
  float* bnO = bnA + DD;
  unsigned short* Mp = (unsigned short*)(bnO + DD);        // 32768 bf16 = 16384 floats
  unsigned short* Up = Mp + 32768;                         // 81920 bf16
  unsigned short* Xp = Up + 81920;                         // 16384 bf16
  unsigned int* cnt    = (unsigned int*)(Xp + 16384);
  unsigned int* off    = cnt + NN;
  unsigned int* cursor = off + NN + 1;
  unsigned int* eidx   = cursor + NN;

  pack_prep<<<128, 256, 0, stream>>>(Mw, Mp);
  pack_u<<<320, 256, 0, stream>>>(Uw, Up);
  pack_mix<<<64, 256, 0, stream>>>(mixw, Xp);

  gemm_prep<<<(NN + 31) / 32, 256, 0, stream>>>(nd, Mp, Mb, A, Bv);

  init_small<<<(NN + 255) / 256, 256, 0, stream>>>(cnt, bns, bnq);
  deg_count<<<(EE + 255) / 256, 256, 0, stream>>>(dst, cnt);
  scan_k<<<1, 1024, 0, stream>>>(cnt, off, cursor);
  fill_k<<<(EE + 255) / 256, 256, 0, stream>>>(src, dst, cursor, eidx);
  aggregate<<<(NN + 3) / 4, 256, 0, stream>>>(A, Bv, off, eidx, S, Xm, amp);

  gemm_u<<<(NN + 63) / 64, 256, 0, stream>>>(nd, S, Xm, amp, Up, Ub, H);
  bn_stats<<<500, 256, 0, stream>>>(H, bns, bnq);
  bn_finalize<<<1, 128, 0, stream>>>(bns, bnq, gamma, beta, bnA, bnO);
  gemm_final<<<(NN + 63) / 64, 256, 0, stream>>>(H, bnA, bnO, Xp, mixb, out);
}

// Round 8
// 479.675 us; speedup vs baseline: 5.3008x; 1.0684x over previous
//
#include <hip/hip_runtime.h>
#include <hip/hip_bf16.h>

#define NN 50000
#define EE 800000
#define DD 128
#define NBLK_SCAN 196   // ceil(NN/256)

typedef short bf8 __attribute__((ext_vector_type(8)));     // 8 bf16 bit-patterns (4 VGPR)
typedef float f32x4 __attribute__((ext_vector_type(4)));

__device__ __forceinline__ unsigned short f2b(float f) {
  __hip_bfloat16 h = __float2bfloat16(f);
  return *reinterpret_cast<unsigned short*>(&h);
}

__device__ __forceinline__ bf8 mk_a(const float* __restrict__ p, float sc) {
  float4 x0 = *(const float4*)p;
  float4 x1 = *(const float4*)(p + 4);
  bf8 a;
  a[0] = (short)f2b(x0.x * sc); a[1] = (short)f2b(x0.y * sc);
  a[2] = (short)f2b(x0.z * sc); a[3] = (short)f2b(x0.w * sc);
  a[4] = (short)f2b(x1.x * sc); a[5] = (short)f2b(x1.y * sc);
  a[6] = (short)f2b(x1.z * sc); a[7] = (short)f2b(x1.w * sc);
  return a;
}

// ---------- one-shot setup: pack all weights to B-fragment order + zero cnt/bns/bnq ----
// B-frag layout: out[((kt*N16+ct)*64+l)*8+j] = W(k = kt*32+(l>>4)*8+j , c = ct*16+(l&15))
__global__ __launch_bounds__(256) void pack_all(
    const float* __restrict__ Mw, const float* __restrict__ Uw, const float* __restrict__ Mixw,
    unsigned short* __restrict__ Mp, unsigned short* __restrict__ Up,
    unsigned short* __restrict__ Xp, unsigned int* __restrict__ cnt,
    float* __restrict__ bns, float* __restrict__ bnq) {
  int gid = blockIdx.x * 256 + threadIdx.x;
  if (gid < NN) cnt[gid] = 0u;
  if (gid < DD) { bns[gid] = 0.f; bnq[gid] = 0.f; }
  if (gid < 32768) {
    // prep weights: N=256 ([Mw_top | Mw_bot]), K=128
    int g = gid;
    int j = g & 7, l = (g >> 3) & 63, ct = (g >> 9) & 15, kt = g >> 13;
    int k = kt * 32 + ((l >> 4) << 3) + j;
    int c = ct * 16 + (l & 15);
    float v = (c < 128) ? Mw[k * DD + c] : Mw[(128 + k) * DD + (c - 128)];
    Mp[g] = f2b(v);
  } else if (gid < 32768 + 81920) {
    // U combined: K=640 panels [W0; W1+W3; W4+W6; W2; W5], N=128
    int g = gid - 32768;
    int j = g & 7, l = (g >> 3) & 63, ct = (g >> 9) & 7, kt = g >> 12;
    int k = kt * 32 + ((l >> 4) << 3) + j;
    int p = k >> 7, kk = k & 127;
    int c = ct * 16 + (l & 15);
    float v;
    switch (p) {
      case 0: v = Uw[kk * DD + c]; break;
      case 1: v = Uw[(128 + kk) * DD + c] + Uw[(384 + kk) * DD + c]; break;
      case 2: v = Uw[(512 + kk) * DD + c] + Uw[(768 + kk) * DD + c]; break;
      case 3: v = Uw[(256 + kk) * DD + c]; break;
      default: v = Uw[(640 + kk) * DD + c]; break;
    }
    Up[g] = f2b(v);
  } else if (gid < 131072) {
    // mix: K=128, N=128
    int g = gid - 114688;
    int j = g & 7, l = (g >> 3) & 63, ct = (g >> 9) & 7, kt = g >> 12;
    int k = kt * 32 + ((l >> 4) << 3) + j;
    int c = ct * 16 + (l & 15);
    Xp[g] = f2b(Mixw[k * DD + c]);
  }
}

// ---------- gemm_prep : A = nd@Mw_top ; Bv = nd@Mw_bot + Mb ----------
__global__ __launch_bounds__(256) void gemm_prep(
    const float* __restrict__ nd, const unsigned short* __restrict__ Mp,
    const float* __restrict__ Mb, float* __restrict__ A, float* __restrict__ Bv) {
  const int w = threadIdx.x >> 6, l = threadIdx.x & 63;
  const int half = w >> 1;
  const int row0 = blockIdx.x * 32 + (w & 1) * 16;
  const int rc = min(row0 + (l & 15), NN - 1);
  const int ko = (l >> 4) * 8;
  const bf8* B8 = (const bf8*)Mp;
  f32x4 zero = {0.f, 0.f, 0.f, 0.f};
  f32x4 acc[8];
  #pragma unroll
  for (int i = 0; i < 8; i++) acc[i] = zero;
  #pragma unroll
  for (int ks = 0; ks < 4; ks++) {
    bf8 a = mk_a(nd + (size_t)rc * DD + ks * 32 + ko, 1.f);
    #pragma unroll
    for (int ct = 0; ct < 8; ct++) {
      bf8 b = B8[(ks * 16 + half * 8 + ct) * 64 + l];
      acc[ct] = __builtin_amdgcn_mfma_f32_16x16x32_bf16(a, b, acc[ct], 0, 0, 0);
    }
  }
  const int rb = row0 + (l >> 4) * 4;
  float* outp = half ? Bv : A;
  #pragma unroll
  for (int ct = 0; ct < 8; ct++) {
    int c = ct * 16 + (l & 15);
    float bias = half ? Mb[c] : 0.f;
    #pragma unroll
    for (int jj = 0; jj < 4; jj++) {
      int rr = rb + jj;
      if (rr < NN) outp[(size_t)rr * DD + c] = acc[ct][jj] + bias;
    }
  }
}

__global__ __launch_bounds__(256) void deg_count(
    const int* __restrict__ dst, unsigned int* __restrict__ cnt) {
  int e = blockIdx.x * 256 + threadIdx.x;
  if (e < EE) atomicAdd(&cnt[dst[e]], 1u);
}

// ---------- hierarchical exclusive scan of cnt[NN] ----------
__global__ __launch_bounds__(256) void scan_blk(
    const unsigned int* __restrict__ cnt, unsigned int* __restrict__ loc,
    unsigned int* __restrict__ bsum) {
  __shared__ unsigned int sh[256];
  const int t = threadIdx.x;
  const int i = blockIdx.x * 256 + t;
  unsigned int v = (i < NN) ? cnt[i] : 0u;
  sh[t] = v;
  __syncthreads();
  for (int d = 1; d < 256; d <<= 1) {
    unsigned int u = (t >= d) ? sh[t - d] : 0u;
    __syncthreads();
    sh[t] += u;
    __syncthreads();
  }
  if (i < NN) loc[i] = sh[t] - v;
  if (t == 255) bsum[blockIdx.x] = sh[255];
}

__global__ __launch_bounds__(256) void scan_top(
    const unsigned int* __restrict__ bsum, unsigned int* __restrict__ bbase) {
  __shared__ unsigned int sh[256];
  const int t = threadIdx.x;
  unsigned int v = (t < NBLK_SCAN) ? bsum[t] : 0u;
  sh[t] = v;
  __syncthreads();
  for (int d = 1; d < 256; d <<= 1) {
    unsigned int u = (t >= d) ? sh[t - d] : 0u;
    __syncthreads();
    sh[t] += u;
    __syncthreads();
  }
  if (t < NBLK_SCAN) bbase[t] = sh[t] - v;
}

__global__ __launch_bounds__(256) void scan_fin(
    const unsigned int* __restrict__ loc, const unsigned int* __restrict__ bbase,
    unsigned int* __restrict__ off, unsigned int* __restrict__ cursor) {
  const int i = blockIdx.x * 256 + threadIdx.x;
  if (i < NN) {
    unsigned int o = loc[i] + bbase[blockIdx.x];
    off[i] = o; cursor[i] = o;
  }
  if (i == 0) off[NN] = EE;
}

__global__ __launch_bounds__(256) void fill_k(
    const int* __restrict__ src, const int* __restrict__ dst,
    unsigned int* __restrict__ cursor, unsigned int* __restrict__ eidx) {
  int e = blockIdx.x * 256 + threadIdx.x;
  if (e < EE) {
    unsigned int p = atomicAdd(&cursor[dst[e]], 1u);
    eidx[p] = (unsigned int)src[e];
  }
}

// gather-aggregate: one wave per node
__global__ __launch_bounds__(256) void aggregate(
    const float* __restrict__ A, const float* __restrict__ Bv,
    const unsigned int* __restrict__ off, const unsigned int* __restrict__ eidx,
    float* __restrict__ S, float* __restrict__ Xm, float* __restrict__ amp) {
  int wave = threadIdx.x >> 6, lane = threadIdx.x & 63;
  int n = blockIdx.x * 4 + wave;
  if (n >= NN) return;
  unsigned int b0 = off[n], b1 = off[n + 1];
  float2 sum = ((const float2*)(A + (size_t)n * DD))[lane];
  float2 mx = sum;
  for (unsigned int j0 = b0; j0 < b1; j0 += 64) {
    int m = (int)min(64u, b1 - j0);
    int myi = (lane < m) ? (int)eidx[j0 + lane] : 0;
    for (int j = 0; j < m; j++) {
      int sN = __shfl(myi, j);
      float2 a = ((const float2*)(A + (size_t)sN * DD))[lane];
      sum.x += a.x; sum.y += a.y;
      mx.x = fmaxf(mx.x, a.x); mx.y = fmaxf(mx.y, a.y);
    }
  }
  float degf = (float)(b1 - b0) + 1.f;
  float inv = 1.f / degf;
  float2 b = ((const float2*)(Bv + (size_t)n * DD))[lane];
  float2 sm = {sum.x * inv + b.x, sum.y * inv + b.y};
  float2 xm = {mx.x + b.x, mx.y + b.y};
  ((float2*)(S + (size_t)n * DD))[lane] = sm;
  ((float2*)(Xm + (size_t)n * DD))[lane] = xm;
  if (lane == 0) amp[n] = logf(degf + 1.f) * 0.4f;
}

// ---------- gemm_u : H = [nd|S|amp*S|Xm|amp*Xm] @ Uc + Ub ; fused BN stats ----------
__global__ __launch_bounds__(256) void gemm_u(
    const float* __restrict__ nd, const float* __restrict__ S, const float* __restrict__ Xm,
    const float* __restrict__ amp, const unsigned short* __restrict__ Up,
    const float* __restrict__ Ub, float* __restrict__ H,
    float* __restrict__ bns, float* __restrict__ bnq) {
  const int w = threadIdx.x >> 6, l = threadIdx.x & 63;
  const int row0 = blockIdx.x * 64 + w * 16;
  const int rc = min(row0 + (l & 15), NN - 1);
  const int ko = (l >> 4) * 8;
  const float av = amp[rc];
  const bf8* B8 = (const bf8*)Up;
  f32x4 zero = {0.f, 0.f, 0.f, 0.f};
  f32x4 acc[8];
  #pragma unroll
  for (int i = 0; i < 8; i++) acc[i] = zero;

  #pragma unroll 1
  for (int p = 0; p < 5; p++) {
    const float* sp = (p == 0) ? nd : (p < 3) ? S : Xm;
    const float sc = (p == 2 || p == 4) ? av : 1.f;
    const float* base = sp + (size_t)rc * DD + ko;
    #pragma unroll
    for (int q = 0; q < 4; q++) {
      bf8 a = mk_a(base + q * 32, sc);
      const int ks = p * 4 + q;
      #pragma unroll
      for (int ct = 0; ct < 8; ct++) {
        bf8 b = B8[(ks * 8 + ct) * 64 + l];
        acc[ct] = __builtin_amdgcn_mfma_f32_16x16x32_bf16(a, b, acc[ct], 0, 0, 0);
      }
    }
  }
  const int rb = row0 + (l >> 4) * 4;
  #pragma unroll
  for (int ct = 0; ct < 8; ct++) {
    int c = ct * 16 + (l & 15);
    float ub = Ub[c];
    float sS = 0.f, sQ = 0.f;
    #pragma unroll
    for (int jj = 0; jj < 4; jj++) {
      int rr = rb + jj;
      if (rr < NN) {
        float h = acc[ct][jj] + ub;
        H[(size_t)rr * DD + c] = h;
        sS += h; sQ += h * h;
      }
    }
    // reduce across the 4 lanes sharing channel c (l^16, l^32)
    sS += __shfl_xor(sS, 16); sS += __shfl_xor(sS, 32);
    sQ += __shfl_xor(sQ, 16); sQ += __shfl_xor(sQ, 32);
    if ((l >> 4) == 0) {
      atomicAdd(bns + c, sS);
      atomicAdd(bnq + c, sQ);
    }
  }
}

// ---------- gemm_final : out = leaky( BN(H) @ mixw + mixb ), BN affine inline ------
__global__ __launch_bounds__(256) void gemm_final(
    const float* __restrict__ H, const float* __restrict__ bns, const float* __restrict__ bnq,
    const float* __restrict__ gamma, const float* __restrict__ beta,
    const unsigned short* __restrict__ Xp, const float* __restrict__ mixb,
    float* __restrict__ out) {
  const int w = threadIdx.x >> 6, l = threadIdx.x & 63;
  const int row0 = blockIdx.x * 64 + w * 16;
  const int rc = min(row0 + (l & 15), NN - 1);
  const int ko = (l >> 4) * 8;
  const bf8* B8 = (const bf8*)Xp;
  const float invN = 1.f / (float)NN;
  f32x4 zero = {0.f, 0.f, 0.f, 0.f};
  f32x4 acc[8];
  #pragma unroll
  for (int i = 0; i < 8; i++) acc[i] = zero;

  // per-lane BN affine for its 32 k-channels (computed once, reused over ks)
  float aA[8], aO[8];
  #pragma unroll
  for (int ks = 0; ks < 4; ks++) {
    const int kch = ks * 32 + ko;
    if (ks == 0) {}  // keep loop structure simple
  }
  #pragma unroll
  for (int ks = 0; ks < 4; ks++) {
    const int kch = ks * 32 + ko;
    #pragma unroll
    for (int j = 0; j < 8; j++) {
      int c = kch + j;
      float mu = bns[c] * invN;
      float var = bnq[c] * invN - mu * mu;
      float a = gamma[c] * rsqrtf(var + 1e-5f);
      aA[j] = a; aO[j] = beta[c] - mu * a;
    }
    const float* p = H + (size_t)rc * DD + kch;
    float4 x0 = *(const float4*)p;
    float4 x1 = *(const float4*)(p + 4);
    bf8 a;
    a[0] = (short)f2b(x0.x * aA[0] + aO[0]); a[1] = (short)f2b(x0.y * aA[1] + aO[1]);
    a[2] = (short)f2b(x0.z * aA[2] + aO[2]); a[3] = (short)f2b(x0.w * aA[3] + aO[3]);
    a[4] = (short)f2b(x1.x * aA[4] + aO[4]); a[5] = (short)f2b(x1.y * aA[5] + aO[5]);
    a[6] = (short)f2b(x1.z * aA[6] + aO[6]); a[7] = (short)f2b(x1.w * aA[7] + aO[7]);
    #pragma unroll
    for (int ct = 0; ct < 8; ct++) {
      bf8 b = B8[(ks * 8 + ct) * 64 + l];
      acc[ct] = __builtin_amdgcn_mfma_f32_16x16x32_bf16(a, b, acc[ct], 0, 0, 0);
    }
  }
  const int rb = row0 + (l >> 4) * 4;
  #pragma unroll
  for (int ct = 0; ct < 8; ct++) {
    int c = ct * 16 + (l & 15);
    float mbv = mixb[c];
    #pragma unroll
    for (int jj = 0; jj < 4; jj++) {
      int rr = rb + jj;
      if (rr < NN) {
        float o = acc[ct][jj] + mbv;
        o = o > 0.f ? o : 0.01f * o;
        out[(size_t)rr * DD + c] = o;
      }
    }
  }
}

extern "C" void kernel_launch(void* const* d_in, const int* in_sizes, int n_in,
                              void* d_out, int out_size, void* d_ws, size_t ws_size,
                              hipStream_t stream) {
  const float* nd    = (const float*)d_in[0];
  const float* Mw    = (const float*)d_in[1];
  const float* Mb    = (const float*)d_in[2];
  const float* Uw    = (const float*)d_in[3];
  const float* Ub    = (const float*)d_in[4];
  const float* gamma = (const float*)d_in[5];
  const float* beta  = (const float*)d_in[6];
  const float* mixw  = (const float*)d_in[7];
  const float* mixb  = (const float*)d_in[8];
  const int* src = (const int*)d_in[9];
  const int* dst = (const int*)d_in[10];
  float* out = (float*)d_out;

  float* ws  = (float*)d_ws;
  float* A   = ws;
  float* Bv  = A + (size_t)NN * DD;
  float* S   = Bv + (size_t)NN * DD;
  float* Xm  = S + (size_t)NN * DD;
  float* H   = Xm + (size_t)NN * DD;
  float* amp = H + (size_t)NN * DD;
  float* bns = amp + NN;
  float* bnq = bns + DD;
  unsigned short* Mp = (unsigned short*)(bnq + DD);        // 32768 bf16
  unsigned short* Up = Mp + 32768;                         // 81920 bf16
  unsigned short* Xp = Up + 81920;                         // 16384 bf16
  unsigned int* cnt    = (unsigned int*)(Xp + 16384);
  unsigned int* off    = cnt + NN;
  unsigned int* cursor = off + NN + 1;
  unsigned int* eidx   = cursor + NN;
  unsigned int* loc    = eidx + EE;
  unsigned int* bsum   = loc + NN;
  unsigned int* bbase  = bsum + 256;

  pack_all<<<512, 256, 0, stream>>>(Mw, Uw, mixw, Mp, Up, Xp, cnt, bns, bnq);
  gemm_prep<<<(NN + 31) / 32, 256, 0, stream>>>(nd, Mp, Mb, A, Bv);
  deg_count<<<(EE + 255) / 256, 256, 0, stream>>>(dst, cnt);
  scan_blk<<<NBLK_SCAN, 256, 0, stream>>>(cnt, loc, bsum);
  scan_top<<<1, 256, 0, stream>>>(bsum, bbase);
  scan_fin<<<NBLK_SCAN, 256, 0, stream>>>(loc, bbase, off, cursor);
  fill_k<<<(EE + 255) / 256, 256, 0, stream>>>(src, dst, cursor, eidx);
  aggregate<<<(NN + 3) / 4, 256, 0, stream>>>(A, Bv, off, eidx, S, Xm, amp);
  gemm_u<<<(NN + 63) / 64, 256, 0, stream>>>(nd, S, Xm, amp, Up, Ub, H, bns, bnq);
  gemm_final<<<(NN + 63) / 64, 256, 0, stream>>>(H, bns, bnq, gamma, beta, Xp, mixb, out);
}

// Round 11
// 435.556 us; speedup vs baseline: 5.8377x; 1.1013x over previous
//
#include <hip/hip_runtime.h>
#include <hip/hip_bf16.h>

#define NN 50000
#define EE 800000
#define DD 128
#define NT 3125          // NN/16 row-tiles (exact)
#define NBLK_SCAN 196    // ceil(NN/256)

typedef short bf8 __attribute__((ext_vector_type(8)));     // 8 bf16 (4 VGPR) = A/B frag
typedef float f32x4 __attribute__((ext_vector_type(4)));

__device__ __forceinline__ unsigned short f2b(float f) {
  __hip_bfloat16 h = __float2bfloat16(f);
  return *reinterpret_cast<unsigned short*>(&h);
}
__device__ __forceinline__ float b2f_bits(unsigned short s) {
  return __uint_as_float(((unsigned int)s) << 16);
}
__device__ __forceinline__ unsigned int pack2(float x, float y) {
  return (unsigned int)f2b(x) | ((unsigned int)f2b(y) << 16);
}

// ---------- pack_all: weights -> B-frag order bf16 ; zero cnt/bns/bnq ----------
// B-frag: out[(kt*NCT+ct)*512 + l*8 + j] = W(k = kt*32+(l>>4)*8+j , c = ct*16+(l&15))
__global__ __launch_bounds__(256) void pack_all(
    const float* __restrict__ Mw, const float* __restrict__ Uw, const float* __restrict__ Mixw,
    unsigned short* __restrict__ Mp, unsigned short* __restrict__ Ui,
    unsigned short* __restrict__ Ua, unsigned short* __restrict__ Xx,
    unsigned int* __restrict__ cnt, float* __restrict__ bns, float* __restrict__ bnq) {
  int gid = blockIdx.x * 256 + threadIdx.x;
  if (gid < NN) cnt[gid] = 0u;
  if (gid < DD) { bns[gid] = 0.f; bnq[gid] = 0.f; }
  if (gid < 32768) {               // Mp: K=128, N=256 ([Mw_top | Mw_bot])
    int g = gid;
    int j = g & 7, l = (g >> 3) & 63, ct = (g >> 9) & 15, kt = g >> 13;
    int k = kt * 32 + ((l >> 4) << 3) + j;
    int c = ct * 16 + (l & 15);
    float v = (c < 128) ? Mw[k * DD + c] : Mw[(128 + k) * DD + (c - 128)];
    Mp[g] = f2b(v);
  } else if (gid < 81920) {        // Ui: K=384 [W0; W1+W3; W2], N=128
    int g = gid - 32768;
    int j = g & 7, l = (g >> 3) & 63, ct = (g >> 9) & 7, kt = g >> 12;
    int k = kt * 32 + ((l >> 4) << 3) + j;      // 0..383
    int c = ct * 16 + (l & 15);
    float v = Uw[k * DD + c];
    if (k >= 128 && k < 256) v += Uw[(k + 256) * DD + c];
    Ui[g] = f2b(v);
  } else if (gid < 114688) {       // Ua: K=256 [W4+W6; W5], N=128
    int g = gid - 81920;
    int j = g & 7, l = (g >> 3) & 63, ct = (g >> 9) & 7, kt = g >> 12;
    int k = kt * 32 + ((l >> 4) << 3) + j;      // 0..255
    int c = ct * 16 + (l & 15);
    float v = Uw[(512 + k) * DD + c];
    if (k < 128) v += Uw[(768 + k) * DD + c];
    Ua[g] = f2b(v);
  } else if (gid < 131072) {       // mix: K=128, N=128
    int g = gid - 114688;
    int j = g & 7, l = (g >> 3) & 63, ct = (g >> 9) & 7, kt = g >> 12;
    int k = kt * 32 + ((l >> 4) << 3) + j;
    int c = ct * 16 + (l & 15);
    Xx[g] = f2b(Mixw[k * DD + c]);
  }
}

// ---------- pack_nd: ndata fp32 row-major -> packed A-frag bf16 ----------
// packed uint idx: tile*1024 + ks*256 + l*4 + (ln&3) ; l = ((ln>>2)&3)*16 + (n&15), ks=ln>>4
__global__ __launch_bounds__(256) void pack_nd(
    const float* __restrict__ nd, unsigned int* __restrict__ ndp) {
  int gid = blockIdx.x * 256 + threadIdx.x;          // over NN*64 pairs
  int n = gid >> 6, ln = gid & 63;
  float2 v = ((const float2*)nd)[gid];
  int uidx = (n >> 4) * 1024 + (ln >> 4) * 256 + (((ln >> 2) & 3) * 16 + (n & 15)) * 4 + (ln & 3);
  ndp[uidx] = pack2(v.x, v.y);
}

// ---------- gemm_prep : A16 = bf16(nd@Mw_top) ; Bv = nd@Mw_bot + Mb ----------
__global__ __launch_bounds__(256) void gemm_prep(
    const unsigned short* __restrict__ ndp, const unsigned short* __restrict__ Mp,
    const float* __restrict__ Mb, unsigned short* __restrict__ A16, float* __restrict__ Bv) {
  const int w = threadIdx.x >> 6, l = threadIdx.x & 63;
  const int half = w >> 1, strip = w & 1;
  const int row0 = blockIdx.x * 32 + strip * 16;
  const int tile = min(blockIdx.x * 2 + strip, NT - 1);
  const bf8* AP = (const bf8*)ndp;
  const bf8* B8 = (const bf8*)Mp;
  f32x4 zero = {0.f, 0.f, 0.f, 0.f};
  f32x4 acc[8];
  #pragma unroll
  for (int i = 0; i < 8; i++) acc[i] = zero;
  #pragma unroll
  for (int ks = 0; ks < 4; ks++) {
    bf8 a = AP[tile * 256 + ks * 64 + l];
    #pragma unroll
    for (int ct = 0; ct < 8; ct++) {
      bf8 b = B8[(ks * 16 + half * 8 + ct) * 64 + l];
      acc[ct] = __builtin_amdgcn_mfma_f32_16x16x32_bf16(a, b, acc[ct], 0, 0, 0);
    }
  }
  const int rb = row0 + (l >> 4) * 4;
  #pragma unroll
  for (int ct = 0; ct < 8; ct++) {
    int c = ct * 16 + (l & 15);
    float bias = half ? Mb[c] : 0.f;
    #pragma unroll
    for (int jj = 0; jj < 4; jj++) {
      int rr = rb + jj;
      if (rr < NN) {
        float v = acc[ct][jj] + bias;
        if (half) Bv[(size_t)rr * DD + c] = v;
        else      A16[(size_t)rr * DD + c] = f2b(v);
      }
    }
  }
}

__global__ __launch_bounds__(256) void deg_count(
    const int* __restrict__ dst, unsigned int* __restrict__ cnt) {
  int e = blockIdx.x * 256 + threadIdx.x;
  if (e < EE) atomicAdd(&cnt[dst[e]], 1u);
}

// ---------- hierarchical exclusive scan ----------
__global__ __launch_bounds__(256) void scan_blk(
    const unsigned int* __restrict__ cnt, unsigned int* __restrict__ loc,
    unsigned int* __restrict__ bsum) {
  __shared__ unsigned int sh[256];
  const int t = threadIdx.x;
  const int i = blockIdx.x * 256 + t;
  unsigned int v = (i < NN) ? cnt[i] : 0u;
  sh[t] = v;
  __syncthreads();
  for (int d = 1; d < 256; d <<= 1) {
    unsigned int u = (t >= d) ? sh[t - d] : 0u;
    __syncthreads();
    sh[t] += u;
    __syncthreads();
  }
  if (i < NN) loc[i] = sh[t] - v;
  if (t == 255) bsum[blockIdx.x] = sh[255];
}

__global__ __launch_bounds__(256) void scan_top(
    const unsigned int* __restrict__ bsum, unsigned int* __restrict__ bbase) {
  __shared__ unsigned int sh[256];
  const int t = threadIdx.x;
  unsigned int v = (t < NBLK_SCAN) ? bsum[t] : 0u;
  sh[t] = v;
  __syncthreads();
  for (int d = 1; d < 256; d <<= 1) {
    unsigned int u = (t >= d) ? sh[t - d] : 0u;
    __syncthreads();
    sh[t] += u;
    __syncthreads();
  }
  if (t < NBLK_SCAN) bbase[t] = sh[t] - v;
}

__global__ __launch_bounds__(256) void scan_fin(
    const unsigned int* __restrict__ loc, const unsigned int* __restrict__ bbase,
    unsigned int* __restrict__ off, unsigned int* __restrict__ cursor) {
  const int i = blockIdx.x * 256 + threadIdx.x;
  if (i < NN) {
    unsigned int o = loc[i] + bbase[blockIdx.x];
    off[i] = o; cursor[i] = o;
  }
  if (i == 0) off[NN] = EE;
}

__global__ __launch_bounds__(256) void fill_k(
    const int* __restrict__ src, const int* __restrict__ dst,
    unsigned int* __restrict__ cursor, unsigned int* __restrict__ eidx) {
  int e = blockIdx.x * 256 + threadIdx.x;
  if (e < EE) {
    unsigned int p = atomicAdd(&cursor[dst[e]], 1u);
    eidx[p] = (unsigned int)src[e];
  }
}

// ---------- aggregate: gather bf16 A rows; write S/Xm in packed A-frag bf16 ----------
__global__ __launch_bounds__(256) void aggregate(
    const unsigned short* __restrict__ A16, const float* __restrict__ Bv,
    const unsigned int* __restrict__ off, const unsigned int* __restrict__ eidx,
    unsigned int* __restrict__ Sp, unsigned int* __restrict__ Xmp,
    float* __restrict__ amp) {
  int wave = threadIdx.x >> 6, ln = threadIdx.x & 63;
  int n = blockIdx.x * 4 + wave;
  if (n >= NN) return;
  const unsigned int* Au = (const unsigned int*)A16;
  unsigned int b0 = off[n], b1 = off[n + 1];
  unsigned int su = Au[(size_t)n * 64 + ln];
  float sx = b2f_bits((unsigned short)su), sy = b2f_bits((unsigned short)(su >> 16));
  float sumx = sx, sumy = sy, mxx = sx, mxy = sy;
  for (unsigned int j0 = b0; j0 < b1; j0 += 64) {
    int m = (int)min(64u, b1 - j0);
    int myi = (ln < m) ? (int)eidx[j0 + ln] : 0;
    for (int j = 0; j < m; j++) {
      int sN = __shfl(myi, j);
      unsigned int au = Au[(size_t)sN * 64 + ln];
      float ax = b2f_bits((unsigned short)au), ay = b2f_bits((unsigned short)(au >> 16));
      sumx += ax; sumy += ay;
      mxx = fmaxf(mxx, ax); mxy = fmaxf(mxy, ay);
    }
  }
  float degf = (float)(b1 - b0) + 1.f;
  float inv = 1.f / degf;
  float2 b = ((const float2*)(Bv + (size_t)n * DD))[ln];
  float smx = sumx * inv + b.x, smy = sumy * inv + b.y;
  float xmx = mxx + b.x, xmy = mxy + b.y;
  int uidx = (n >> 4) * 1024 + (ln >> 4) * 256 + (((ln >> 2) & 3) * 16 + (n & 15)) * 4 + (ln & 3);
  Sp[uidx] = pack2(smx, smy);
  Xmp[uidx] = pack2(xmx, xmy);
  if (ln == 0) amp[n] = logf(degf + 1.f) * 0.4f;
}

// ---------- gemm_u : accI(K=384: nd,S,Xm) + amp*accA(K=256: S,Xm) + Ub ----------
// writes Hp packed bf16 ; fused BN stats
__global__ __launch_bounds__(256) void gemm_u(
    const unsigned short* __restrict__ ndp, const unsigned short* __restrict__ Sp,
    const unsigned short* __restrict__ Xmp, const float* __restrict__ amp,
    const unsigned short* __restrict__ Ui, const unsigned short* __restrict__ Ua,
    const float* __restrict__ Ub, unsigned short* __restrict__ Hp,
    float* __restrict__ bns, float* __restrict__ bnq) {
  const int w = threadIdx.x >> 6, l = threadIdx.x & 63;
  const int row0 = blockIdx.x * 64 + w * 16;
  const int tile = min(blockIdx.x * 4 + w, NT - 1);
  const bf8* ND = (const bf8*)ndp;
  const bf8* SS = (const bf8*)Sp;
  const bf8* XX = (const bf8*)Xmp;
  const bf8* BI = (const bf8*)Ui;
  const bf8* BA = (const bf8*)Ua;
  f32x4 zero = {0.f, 0.f, 0.f, 0.f};
  f32x4 accI[8], accA[8];
  #pragma unroll
  for (int i = 0; i < 8; i++) { accI[i] = zero; accA[i] = zero; }

  #pragma unroll
  for (int ks = 0; ks < 4; ks++) {               // panel nd -> accI (Ui k-slices 0..3)
    bf8 a = ND[tile * 256 + ks * 64 + l];
    #pragma unroll
    for (int ct = 0; ct < 8; ct++)
      accI[ct] = __builtin_amdgcn_mfma_f32_16x16x32_bf16(a, BI[(ks * 8 + ct) * 64 + l], accI[ct], 0, 0, 0);
  }
  #pragma unroll
  for (int ks = 0; ks < 4; ks++) {               // panel S -> accI (4..7) + accA (0..3)
    bf8 a = SS[tile * 256 + ks * 64 + l];
    #pragma unroll
    for (int ct = 0; ct < 8; ct++)
      accI[ct] = __builtin_amdgcn_mfma_f32_16x16x32_bf16(a, BI[((4 + ks) * 8 + ct) * 64 + l], accI[ct], 0, 0, 0);
    #pragma unroll
    for (int ct = 0; ct < 8; ct++)
      accA[ct] = __builtin_amdgcn_mfma_f32_16x16x32_bf16(a, BA[(ks * 8 + ct) * 64 + l], accA[ct], 0, 0, 0);
  }
  #pragma unroll
  for (int ks = 0; ks < 4; ks++) {               // panel Xm -> accI (8..11) + accA (4..7)
    bf8 a = XX[tile * 256 + ks * 64 + l];
    #pragma unroll
    for (int ct = 0; ct < 8; ct++)
      accI[ct] = __builtin_amdgcn_mfma_f32_16x16x32_bf16(a, BI[((8 + ks) * 8 + ct) * 64 + l], accI[ct], 0, 0, 0);
    #pragma unroll
    for (int ct = 0; ct < 8; ct++)
      accA[ct] = __builtin_amdgcn_mfma_f32_16x16x32_bf16(a, BA[((4 + ks) * 8 + ct) * 64 + l], accA[ct], 0, 0, 0);
  }

  const int rb = row0 + (l >> 4) * 4;
  float ampv[4];
  #pragma unroll
  for (int jj = 0; jj < 4; jj++) ampv[jj] = amp[min(rb + jj, NN - 1)];

  #pragma unroll
  for (int ct = 0; ct < 8; ct++) {
    int c = ct * 16 + (l & 15);
    float ub = Ub[c];
    int hks = ct >> 1;
    int lpb = ((2 * ct + ((l >> 3) & 1)) & 3) * 16 + (l >> 4) * 4;
    int hj = l & 7;
    float sS = 0.f, sQ = 0.f;
    #pragma unroll
    for (int jj = 0; jj < 4; jj++) {
      int rr = rb + jj;
      if (rr < NN) {
        float h = accI[ct][jj] + ampv[jj] * accA[ct][jj] + ub;
        Hp[(size_t)tile * 2048 + hks * 512 + (lpb + jj) * 8 + hj] = f2b(h);
        sS += h; sQ += h * h;
      }
    }
    sS += __shfl_xor(sS, 16); sS += __shfl_xor(sS, 32);
    sQ += __shfl_xor(sQ, 16); sQ += __shfl_xor(sQ, 32);
    if ((l >> 4) == 0) {
      atomicAdd(bns + c, sS);
      atomicAdd(bnq + c, sQ);
    }
  }
}

// ---------- gemm_final : out = leaky( BN(Hp) @ mixw + mixb ) ----------
__global__ __launch_bounds__(256) void gemm_final(
    const unsigned short* __restrict__ Hp, const float* __restrict__ bns,
    const float* __restrict__ bnq, const float* __restrict__ gamma,
    const float* __restrict__ beta, const unsigned short* __restrict__ Xx,
    const float* __restrict__ mixb, float* __restrict__ out) {
  const int w = threadIdx.x >> 6, l = threadIdx.x & 63;
  const int row0 = blockIdx.x * 64 + w * 16;
  const int tile = min(blockIdx.x * 4 + w, NT - 1);
  const bf8* HP = (const bf8*)Hp;
  const bf8* B8 = (const bf8*)Xx;
  const float invN = 1.f / (float)NN;
  f32x4 zero = {0.f, 0.f, 0.f, 0.f};
  f32x4 acc[8];
  #pragma unroll
  for (int i = 0; i < 8; i++) acc[i] = zero;

  #pragma unroll
  for (int ks = 0; ks < 4; ks++) {
    bf8 hp = HP[tile * 256 + ks * 64 + l];
    const int cb = ks * 32 + (l >> 4) * 8;
    bf8 a;
    #pragma unroll
    for (int j = 0; j < 8; j++) {
      int c = cb + j;
      float mu = bns[c] * invN;
      float var = bnq[c] * invN - mu * mu;
      float sc = gamma[c] * rsqrtf(var + 1e-5f);
      float ofs = beta[c] - mu * sc;
      float h = b2f_bits((unsigned short)hp[j]);
      a[j] = (short)f2b(fmaf(h, sc, ofs));
    }
    #pragma unroll
    for (int ct = 0; ct < 8; ct++)
      acc[ct] = __builtin_amdgcn_mfma_f32_16x16x32_bf16(a, B8[(ks * 8 + ct) * 64 + l], acc[ct], 0, 0, 0);
  }
  const int rb = row0 + (l >> 4) * 4;
  #pragma unroll
  for (int ct = 0; ct < 8; ct++) {
    int c = ct * 16 + (l & 15);
    float mbv = mixb[c];
    #pragma unroll
    for (int jj = 0; jj < 4; jj++) {
      int rr = rb + jj;
      if (rr < NN) {
        float o = acc[ct][jj] + mbv;
        o = o > 0.f ? o : 0.01f * o;
        out[(size_t)rr * DD + c] = o;
      }
    }
  }
}

extern "C" void kernel_launch(void* const* d_in, const int* in_sizes, int n_in,
                              void* d_out, int out_size, void* d_ws, size_t ws_size,
                              hipStream_t stream) {
  const float* nd    = (const float*)d_in[0];
  const float* Mw    = (const float*)d_in[1];
  const float* Mb    = (const float*)d_in[2];
  const float* Uw    = (const float*)d_in[3];
  const float* Ub    = (const float*)d_in[4];
  const float* gamma = (const float*)d_in[5];
  const float* beta  = (const float*)d_in[6];
  const float* mixw  = (const float*)d_in[7];
  const float* mixb  = (const float*)d_in[8];
  const int* src = (const int*)d_in[9];
  const int* dst = (const int*)d_in[10];
  float* out = (float*)d_out;

  float* ws  = (float*)d_ws;
  float* Bv  = ws;                                   // NN*DD fp32
  float* amp = Bv + (size_t)NN * DD;                 // NN
  float* bns = amp + NN;                             // DD
  float* bnq = bns + DD;                             // DD
  unsigned short* A16 = (unsigned short*)(bnq + DD); // NN*DD bf16
  unsigned short* ndp = A16 + (size_t)NN * DD;       // NT*2048 bf16
  unsigned short* Sp  = ndp + (size_t)NT * 2048;
  unsigned short* Xmp = Sp + (size_t)NT * 2048;
  unsigned short* Hp  = Xmp + (size_t)NT * 2048;
  unsigned short* Mp  = Hp + (size_t)NT * 2048;      // 32768
  unsigned short* Ui  = Mp + 32768;                  // 49152
  unsigned short* Ua  = Ui + 49152;                  // 32768
  unsigned short* Xx  = Ua + 32768;                  // 16384
  unsigned int* cnt    = (unsigned int*)(Xx + 16384);
  unsigned int* off    = cnt + NN;
  unsigned int* cursor = off + NN + 1;
  unsigned int* eidx   = cursor + NN;
  unsigned int* loc    = eidx + EE;
  unsigned int* bsum   = loc + NN;
  unsigned int* bbase  = bsum + 256;

  pack_all<<<512, 256, 0, stream>>>(Mw, Uw, mixw, Mp, Ui, Ua, Xx, cnt, bns, bnq);
  pack_nd<<<12500, 256, 0, stream>>>(nd, (unsigned int*)ndp);
  gemm_prep<<<(NN + 31) / 32, 256, 0, stream>>>(ndp, Mp, Mb, A16, Bv);
  deg_count<<<(EE + 255) / 256, 256, 0, stream>>>(dst, cnt);
  scan_blk<<<NBLK_SCAN, 256, 0, stream>>>(cnt, loc, bsum);
  scan_top<<<1, 256, 0, stream>>>(bsum, bbase);
  scan_fin<<<NBLK_SCAN, 256, 0, stream>>>(loc, bbase, off, cursor);
  fill_k<<<(EE + 255) / 256, 256, 0, stream>>>(src, dst, cursor, eidx);
  aggregate<<<(NN + 3) / 4, 256, 0, stream>>>(A16, Bv, off, eidx,
                                              (unsigned int*)Sp, (unsigned int*)Xmp, amp);
  gemm_u<<<(NN + 63) / 64, 256, 0, stream>>>(ndp, Sp, Xmp, amp, Ui, Ua, Ub, Hp, bns, bnq);
  gemm_final<<<(NN + 63) / 64, 256, 0, stream>>>(Hp, bns, bnq, gamma, beta, Xx, mixb, out);
}

// Round 12
// 424.894 us; speedup vs baseline: 5.9842x; 1.0251x over previous
//
#include <hip/hip_runtime.h>
#include <hip/hip_bf16.h>

#define NN 50000
#define EE 800000
#define DD 128
#define NT 3125          // NN/16 row-tiles (exact)
#define NBLK_SCAN 196    // ceil(NN/256)

typedef short bf8 __attribute__((ext_vector_type(8)));     // 8 bf16 (4 VGPR) = A/B frag
typedef float f32x4 __attribute__((ext_vector_type(4)));

__device__ __forceinline__ unsigned short f2b(float f) {
  __hip_bfloat16 h = __float2bfloat16(f);
  return *reinterpret_cast<unsigned short*>(&h);
}
__device__ __forceinline__ float b2f_bits(unsigned short s) {
  return __uint_as_float(((unsigned int)s) << 16);
}
__device__ __forceinline__ unsigned int pack2(float x, float y) {
  return (unsigned int)f2b(x) | ((unsigned int)f2b(y) << 16);
}

// ---------- pack_all: weights -> B-frag order bf16 ; zero cnt/bns/bnq ----------
__global__ __launch_bounds__(256) void pack_all(
    const float* __restrict__ Mw, const float* __restrict__ Uw, const float* __restrict__ Mixw,
    unsigned short* __restrict__ Mp, unsigned short* __restrict__ Ui,
    unsigned short* __restrict__ Ua, unsigned short* __restrict__ Xx,
    unsigned int* __restrict__ cnt, float* __restrict__ bns, float* __restrict__ bnq) {
  int gid = blockIdx.x * 256 + threadIdx.x;
  if (gid < NN) cnt[gid] = 0u;
  if (gid < DD) { bns[gid] = 0.f; bnq[gid] = 0.f; }
  if (gid < 32768) {               // Mp: K=128, N=256 ([Mw_top | Mw_bot])
    int g = gid;
    int j = g & 7, l = (g >> 3) & 63, ct = (g >> 9) & 15, kt = g >> 13;
    int k = kt * 32 + ((l >> 4) << 3) + j;
    int c = ct * 16 + (l & 15);
    float v = (c < 128) ? Mw[k * DD + c] : Mw[(128 + k) * DD + (c - 128)];
    Mp[g] = f2b(v);
  } else if (gid < 81920) {        // Ui: K=384 [W0; W1+W3; W2], N=128
    int g = gid - 32768;
    int j = g & 7, l = (g >> 3) & 63, ct = (g >> 9) & 7, kt = g >> 12;
    int k = kt * 32 + ((l >> 4) << 3) + j;
    int c = ct * 16 + (l & 15);
    float v = Uw[k * DD + c];
    if (k >= 128 && k < 256) v += Uw[(k + 256) * DD + c];
    Ui[g] = f2b(v);
  } else if (gid < 114688) {       // Ua: K=256 [W4+W6; W5], N=128
    int g = gid - 81920;
    int j = g & 7, l = (g >> 3) & 63, ct = (g >> 9) & 7, kt = g >> 12;
    int k = kt * 32 + ((l >> 4) << 3) + j;
    int c = ct * 16 + (l & 15);
    float v = Uw[(512 + k) * DD + c];
    if (k < 128) v += Uw[(768 + k) * DD + c];
    Ua[g] = f2b(v);
  } else if (gid < 131072) {       // mix: K=128, N=128
    int g = gid - 114688;
    int j = g & 7, l = (g >> 3) & 63, ct = (g >> 9) & 7, kt = g >> 12;
    int k = kt * 32 + ((l >> 4) << 3) + j;
    int c = ct * 16 + (l & 15);
    Xx[g] = f2b(Mixw[k * DD + c]);
  }
}

// ---------- pack_nd: ndata fp32 row-major -> packed A-frag bf16 ----------
__global__ __launch_bounds__(256) void pack_nd(
    const float* __restrict__ nd, unsigned int* __restrict__ ndp) {
  int gid = blockIdx.x * 256 + threadIdx.x;          // over NN*64 pairs
  int n = gid >> 6, ln = gid & 63;
  float2 v = ((const float2*)nd)[gid];
  int uidx = (n >> 4) * 1024 + (ln >> 4) * 256 + (((ln >> 2) & 3) * 16 + (n & 15)) * 4 + (ln & 3);
  ndp[uidx] = pack2(v.x, v.y);
}

// ---------- gemm_prep : A16 = bf16(nd@Mw_top) (LDS-staged store) ; Bv = nd@Mw_bot + Mb --
__global__ __launch_bounds__(256) void gemm_prep(
    const unsigned short* __restrict__ ndp, const unsigned short* __restrict__ Mp,
    const float* __restrict__ Mb, unsigned short* __restrict__ A16, float* __restrict__ Bv) {
  __shared__ unsigned short alds[32 * DD];   // 8 KB
  const int w = threadIdx.x >> 6, l = threadIdx.x & 63;
  const int half = w >> 1, strip = w & 1;
  const int row0 = blockIdx.x * 32 + strip * 16;
  const int tile = min(blockIdx.x * 2 + strip, NT - 1);
  const bf8* AP = (const bf8*)ndp;
  const bf8* B8 = (const bf8*)Mp;
  f32x4 zero = {0.f, 0.f, 0.f, 0.f};
  f32x4 acc[8];
  #pragma unroll
  for (int i = 0; i < 8; i++) acc[i] = zero;
  #pragma unroll
  for (int ks = 0; ks < 4; ks++) {
    bf8 a = AP[tile * 256 + ks * 64 + l];
    #pragma unroll
    for (int ct = 0; ct < 8; ct++) {
      bf8 b = B8[(ks * 16 + half * 8 + ct) * 64 + l];
      acc[ct] = __builtin_amdgcn_mfma_f32_16x16x32_bf16(a, b, acc[ct], 0, 0, 0);
    }
  }
  const int rl0 = strip * 16 + (l >> 4) * 4;     // row within block tile (0..31)
  const int rb = row0 + (l >> 4) * 4;
  #pragma unroll
  for (int ct = 0; ct < 8; ct++) {
    int c = ct * 16 + (l & 15);
    float bias = half ? Mb[c] : 0.f;
    #pragma unroll
    for (int jj = 0; jj < 4; jj++) {
      int rr = rb + jj;
      if (rr < NN) {
        float v = acc[ct][jj] + bias;
        if (half) Bv[(size_t)rr * DD + c] = v;
        else      alds[(rl0 + jj) * DD + c] = f2b(v);
      }
    }
  }
  __syncthreads();
  // linear coalesced copy of the 32x128 bf16 tile
  const uint4* ls = (const uint4*)alds;
  uint4* gd = (uint4*)(A16 + (size_t)blockIdx.x * 32 * DD);
  #pragma unroll
  for (int e = threadIdx.x; e < 512; e += 256) {
    int r = blockIdx.x * 32 + (e >> 4);
    if (r < NN) gd[e] = ls[e];
  }
}

__global__ __launch_bounds__(256) void deg_count(
    const int* __restrict__ dst, unsigned int* __restrict__ cnt) {
  int e = blockIdx.x * 256 + threadIdx.x;
  if (e < EE) atomicAdd(&cnt[dst[e]], 1u);
}

// ---------- hierarchical exclusive scan ----------
__global__ __launch_bounds__(256) void scan_blk(
    const unsigned int* __restrict__ cnt, unsigned int* __restrict__ loc,
    unsigned int* __restrict__ bsum) {
  __shared__ unsigned int sh[256];
  const int t = threadIdx.x;
  const int i = blockIdx.x * 256 + t;
  unsigned int v = (i < NN) ? cnt[i] : 0u;
  sh[t] = v;
  __syncthreads();
  for (int d = 1; d < 256; d <<= 1) {
    unsigned int u = (t >= d) ? sh[t - d] : 0u;
    __syncthreads();
    sh[t] += u;
    __syncthreads();
  }
  if (i < NN) loc[i] = sh[t] - v;
  if (t == 255) bsum[blockIdx.x] = sh[255];
}

__global__ __launch_bounds__(256) void scan_top(
    const unsigned int* __restrict__ bsum, unsigned int* __restrict__ bbase) {
  __shared__ unsigned int sh[256];
  const int t = threadIdx.x;
  unsigned int v = (t < NBLK_SCAN) ? bsum[t] : 0u;
  sh[t] = v;
  __syncthreads();
  for (int d = 1; d < 256; d <<= 1) {
    unsigned int u = (t >= d) ? sh[t - d] : 0u;
    __syncthreads();
    sh[t] += u;
    __syncthreads();
  }
  if (t < NBLK_SCAN) bbase[t] = sh[t] - v;
}

__global__ __launch_bounds__(256) void scan_fin(
    const unsigned int* __restrict__ loc, const unsigned int* __restrict__ bbase,
    unsigned int* __restrict__ off, unsigned int* __restrict__ cursor) {
  const int i = blockIdx.x * 256 + threadIdx.x;
  if (i < NN) {
    unsigned int o = loc[i] + bbase[blockIdx.x];
    off[i] = o; cursor[i] = o;
  }
  if (i == 0) off[NN] = EE;
}

__global__ __launch_bounds__(256) void fill_k(
    const int* __restrict__ src, const int* __restrict__ dst,
    unsigned int* __restrict__ cursor, unsigned int* __restrict__ eidx) {
  int e = blockIdx.x * 256 + threadIdx.x;
  if (e < EE) {
    unsigned int p = atomicAdd(&cursor[dst[e]], 1u);
    eidx[p] = (unsigned int)src[e];
  }
}

// ---------- aggregate: gather bf16 A rows (8-deep load batching) ----------
__global__ __launch_bounds__(256) void aggregate(
    const unsigned short* __restrict__ A16, const float* __restrict__ Bv,
    const unsigned int* __restrict__ off, const unsigned int* __restrict__ eidx,
    unsigned int* __restrict__ Sp, unsigned int* __restrict__ Xmp,
    float* __restrict__ amp) {
  int wave = threadIdx.x >> 6, ln = threadIdx.x & 63;
  int n = blockIdx.x * 4 + wave;
  if (n >= NN) return;
  const unsigned int* Au = (const unsigned int*)A16;
  unsigned int b0 = off[n], b1 = off[n + 1];
  unsigned int su = Au[(size_t)n * 64 + ln];
  float sx = b2f_bits((unsigned short)su), sy = b2f_bits((unsigned short)(su >> 16));
  float sumx = sx, sumy = sy, mxx = sx, mxy = sy;
  for (unsigned int j0 = b0; j0 < b1; j0 += 64) {
    int m = (int)min(64u, b1 - j0);
    int myi = (ln < m) ? (int)eidx[j0 + ln] : 0;
    int jj = 0;
    for (; jj + 8 <= m; jj += 8) {
      unsigned int av[8];
      #pragma unroll
      for (int q = 0; q < 8; q++) {
        int sN = __shfl(myi, jj + q);
        av[q] = Au[(size_t)sN * 64 + ln];
      }
      #pragma unroll
      for (int q = 0; q < 8; q++) {
        float ax = b2f_bits((unsigned short)av[q]), ay = b2f_bits((unsigned short)(av[q] >> 16));
        sumx += ax; sumy += ay;
        mxx = fmaxf(mxx, ax); mxy = fmaxf(mxy, ay);
      }
    }
    for (; jj < m; jj++) {
      int sN = __shfl(myi, jj);
      unsigned int au = Au[(size_t)sN * 64 + ln];
      float ax = b2f_bits((unsigned short)au), ay = b2f_bits((unsigned short)(au >> 16));
      sumx += ax; sumy += ay;
      mxx = fmaxf(mxx, ax); mxy = fmaxf(mxy, ay);
    }
  }
  float degf = (float)(b1 - b0) + 1.f;
  float inv = 1.f / degf;
  float2 b = ((const float2*)(Bv + (size_t)n * DD))[ln];
  float smx = sumx * inv + b.x, smy = sumy * inv + b.y;
  float xmx = mxx + b.x, xmy = mxy + b.y;
  int uidx = (n >> 4) * 1024 + (ln >> 4) * 256 + (((ln >> 2) & 3) * 16 + (n & 15)) * 4 + (ln & 3);
  Sp[uidx] = pack2(smx, smy);
  Xmp[uidx] = pack2(xmx, xmy);
  if (ln == 0) amp[n] = logf(degf + 1.f) * 0.4f;
}

// ---------- gemm_u : accI(K=384) + amp*accA(K=256) + Ub ; LDS-staged Hp store ; BN stats --
__global__ __launch_bounds__(256) void gemm_u(
    const unsigned short* __restrict__ ndp, const unsigned short* __restrict__ Sp,
    const unsigned short* __restrict__ Xmp, const float* __restrict__ amp,
    const unsigned short* __restrict__ Ui, const unsigned short* __restrict__ Ua,
    const float* __restrict__ Ub, unsigned short* __restrict__ Hp,
    float* __restrict__ bns, float* __restrict__ bnq) {
  __shared__ unsigned short hlds[4 * 2048];   // 16 KB: 4 tiles in packed layout
  const int w = threadIdx.x >> 6, l = threadIdx.x & 63;
  const int row0 = blockIdx.x * 64 + w * 16;
  const int tileIdx = blockIdx.x * 4 + w;
  const bool valid = tileIdx < NT;
  const int tile = valid ? tileIdx : NT - 1;
  const bf8* ND = (const bf8*)ndp;
  const bf8* SS = (const bf8*)Sp;
  const bf8* XX = (const bf8*)Xmp;
  const bf8* BI = (const bf8*)Ui;
  const bf8* BA = (const bf8*)Ua;
  f32x4 zero = {0.f, 0.f, 0.f, 0.f};
  f32x4 accI[8], accA[8];
  #pragma unroll
  for (int i = 0; i < 8; i++) { accI[i] = zero; accA[i] = zero; }

  #pragma unroll
  for (int ks = 0; ks < 4; ks++) {               // panel nd -> accI
    bf8 a = ND[tile * 256 + ks * 64 + l];
    #pragma unroll
    for (int ct = 0; ct < 8; ct++)
      accI[ct] = __builtin_amdgcn_mfma_f32_16x16x32_bf16(a, BI[(ks * 8 + ct) * 64 + l], accI[ct], 0, 0, 0);
  }
  #pragma unroll
  for (int ks = 0; ks < 4; ks++) {               // panel S -> accI + accA
    bf8 a = SS[tile * 256 + ks * 64 + l];
    #pragma unroll
    for (int ct = 0; ct < 8; ct++)
      accI[ct] = __builtin_amdgcn_mfma_f32_16x16x32_bf16(a, BI[((4 + ks) * 8 + ct) * 64 + l], accI[ct], 0, 0, 0);
    #pragma unroll
    for (int ct = 0; ct < 8; ct++)
      accA[ct] = __builtin_amdgcn_mfma_f32_16x16x32_bf16(a, BA[(ks * 8 + ct) * 64 + l], accA[ct], 0, 0, 0);
  }
  #pragma unroll
  for (int ks = 0; ks < 4; ks++) {               // panel Xm -> accI + accA
    bf8 a = XX[tile * 256 + ks * 64 + l];
    #pragma unroll
    for (int ct = 0; ct < 8; ct++)
      accI[ct] = __builtin_amdgcn_mfma_f32_16x16x32_bf16(a, BI[((8 + ks) * 8 + ct) * 64 + l], accI[ct], 0, 0, 0);
    #pragma unroll
    for (int ct = 0; ct < 8; ct++)
      accA[ct] = __builtin_amdgcn_mfma_f32_16x16x32_bf16(a, BA[((4 + ks) * 8 + ct) * 64 + l], accA[ct], 0, 0, 0);
  }

  const int rb = row0 + (l >> 4) * 4;
  float ampv[4];
  #pragma unroll
  for (int jj = 0; jj < 4; jj++) ampv[jj] = amp[min(rb + jj, NN - 1)];

  if (valid) {
    #pragma unroll
    for (int ct = 0; ct < 8; ct++) {
      int c = ct * 16 + (l & 15);
      float ub = Ub[c];
      int hks = ct >> 1;
      int lpb = ((2 * ct + ((l >> 3) & 1)) & 3) * 16 + (l >> 4) * 4;
      int hj = l & 7;
      float sS = 0.f, sQ = 0.f;
      #pragma unroll
      for (int jj = 0; jj < 4; jj++) {
        float h = accI[ct][jj] + ampv[jj] * accA[ct][jj] + ub;
        hlds[w * 2048 + hks * 512 + (lpb + jj) * 8 + hj] = f2b(h);
        sS += h; sQ += h * h;
      }
      sS += __shfl_xor(sS, 16); sS += __shfl_xor(sS, 32);
      sQ += __shfl_xor(sQ, 16); sQ += __shfl_xor(sQ, 32);
      if ((l >> 4) == 0) {
        atomicAdd(bns + c, sS);
        atomicAdd(bnq + c, sQ);
      }
    }
  }
  __syncthreads();
  int ntile = NT - blockIdx.x * 4;
  if (ntile > 4) ntile = 4;
  const uint4* ls = (const uint4*)hlds;
  uint4* gd = (uint4*)(Hp + (size_t)blockIdx.x * 8192);
  for (int e = threadIdx.x; e < ntile * 256; e += 256) gd[e] = ls[e];
}

// ---------- gemm_final : out = leaky( BN(Hp) @ mixw + mixb ) ----------
__global__ __launch_bounds__(256) void gemm_final(
    const unsigned short* __restrict__ Hp, const float* __restrict__ bns,
    const float* __restrict__ bnq, const float* __restrict__ gamma,
    const float* __restrict__ beta, const unsigned short* __restrict__ Xx,
    const float* __restrict__ mixb, float* __restrict__ out) {
  const int w = threadIdx.x >> 6, l = threadIdx.x & 63;
  const int row0 = blockIdx.x * 64 + w * 16;
  const int tile = min(blockIdx.x * 4 + w, NT - 1);
  const bf8* HP = (const bf8*)Hp;
  const bf8* B8 = (const bf8*)Xx;
  const float invN = 1.f / (float)NN;
  f32x4 zero = {0.f, 0.f, 0.f, 0.f};
  f32x4 acc[8];
  #pragma unroll
  for (int i = 0; i < 8; i++) acc[i] = zero;

  #pragma unroll
  for (int ks = 0; ks < 4; ks++) {
    bf8 hp = HP[tile * 256 + ks * 64 + l];
    const int cb = ks * 32 + (l >> 4) * 8;
    bf8 a;
    #pragma unroll
    for (int j = 0; j < 8; j++) {
      int c = cb + j;
      float mu = bns[c] * invN;
      float var = bnq[c] * invN - mu * mu;
      float sc = gamma[c] * rsqrtf(var + 1e-5f);
      float ofs = beta[c] - mu * sc;
      float h = b2f_bits((unsigned short)hp[j]);
      a[j] = (short)f2b(fmaf(h, sc, ofs));
    }
    #pragma unroll
    for (int ct = 0; ct < 8; ct++)
      acc[ct] = __builtin_amdgcn_mfma_f32_16x16x32_bf16(a, B8[(ks * 8 + ct) * 64 + l], acc[ct], 0, 0, 0);
  }
  const int rb = row0 + (l >> 4) * 4;
  #pragma unroll
  for (int ct = 0; ct < 8; ct++) {
    int c = ct * 16 + (l & 15);
    float mbv = mixb[c];
    #pragma unroll
    for (int jj = 0; jj < 4; jj++) {
      int rr = rb + jj;
      if (rr < NN) {
        float o = acc[ct][jj] + mbv;
        o = o > 0.f ? o : 0.01f * o;
        out[(size_t)rr * DD + c] = o;
      }
    }
  }
}

extern "C" void kernel_launch(void* const* d_in, const int* in_sizes, int n_in,
                              void* d_out, int out_size, void* d_ws, size_t ws_size,
                              hipStream_t stream) {
  const float* nd    = (const float*)d_in[0];
  const float* Mw    = (const float*)d_in[1];
  const float* Mb    = (const float*)d_in[2];
  const float* Uw    = (const float*)d_in[3];
  const float* Ub    = (const float*)d_in[4];
  const float* gamma = (const float*)d_in[5];
  const float* beta  = (const float*)d_in[6];
  const float* mixw  = (const float*)d_in[7];
  const float* mixb  = (const float*)d_in[8];
  const int* src = (const int*)d_in[9];
  const int* dst = (const int*)d_in[10];
  float* out = (float*)d_out;

  float* ws  = (float*)d_ws;
  float* Bv  = ws;                                   // NN*DD fp32
  float* amp = Bv + (size_t)NN * DD;                 // NN
  float* bns = amp + NN;                             // DD
  float* bnq = bns + DD;                             // DD
  unsigned short* A16 = (unsigned short*)(bnq + DD); // NN*DD bf16
  unsigned short* ndp = A16 + (size_t)NN * DD;       // NT*2048 bf16
  unsigned short* Sp  = ndp + (size_t)NT * 2048;
  unsigned short* Xmp = Sp + (size_t)NT * 2048;
  unsigned short* Hp  = Xmp + (size_t)NT * 2048;     // NT*2048 + slack (3 tiles) below
  unsigned short* Mp  = Hp + (size_t)(NT + 3) * 2048; // 32768  (slack protects gemm_u tail copy)
  unsigned short* Ui  = Mp + 32768;                  // 49152
  unsigned short* Ua  = Ui + 49152;                  // 32768
  unsigned short* Xx  = Ua + 32768;                  // 16384
  unsigned int* cnt    = (unsigned int*)(Xx + 16384);
  unsigned int* off    = cnt + NN;
  unsigned int* cursor = off + NN + 1;
  unsigned int* eidx   = cursor + NN;
  unsigned int* loc    = eidx + EE;
  unsigned int* bsum   = loc + NN;
  unsigned int* bbase  = bsum + 256;

  pack_all<<<512, 256, 0, stream>>>(Mw, Uw, mixw, Mp, Ui, Ua, Xx, cnt, bns, bnq);
  pack_nd<<<12500, 256, 0, stream>>>(nd, (unsigned int*)ndp);
  gemm_prep<<<(NN + 31) / 32, 256, 0, stream>>>(ndp, Mp, Mb, A16, Bv);
  deg_count<<<(EE + 255) / 256, 256, 0, stream>>>(dst, cnt);
  scan_blk<<<NBLK_SCAN, 256, 0, stream>>>(cnt, loc, bsum);
  scan_top<<<1, 256, 0, stream>>>(bsum, bbase);
  scan_fin<<<NBLK_SCAN, 256, 0, stream>>>(loc, bbase, off, cursor);
  fill_k<<<(EE + 255) / 256, 256, 0, stream>>>(src, dst, cursor, eidx);
  aggregate<<<(NN + 3) / 4, 256, 0, stream>>>(A16, Bv, off, eidx,
                                              (unsigned int*)Sp, (unsigned int*)Xmp, amp);
  gemm_u<<<(NN + 63) / 64, 256, 0, stream>>>(ndp, Sp, Xmp, amp, Ui, Ua, Ub, Hp, bns, bnq);
  gemm_final<<<(NN + 63) / 64, 256, 0, stream>>>(Hp, bns, bnq, gamma, beta, Xx, mixb, out);
}